// Round 6
// baseline (1150.422 us; speedup 1.0000x reference)
//
#include <hip/hip_runtime.h>

#define NP 200000
#define NU 100000
#define NBR 5000
#define NCAT 2000
#define NSH 1000
#define NN (NP + NU + NBR + NCAT + NSH) /* 308000 */
#define OFF_U NP
#define OFF_B (NP + NU)
#define OFF_C (NP + NU + NBR)
#define OFF_S (NP + NU + NBR + NCAT)

#define BIN_SZ 65536    /* records per bin (256KB eidx window) */
#define MAXBINS 64
#define CAP 40          /* LDS staging capacity per bin per batch */
#define OVCAP (1 << 20) /* overflow record capacity */

typedef unsigned short u16;
typedef unsigned int u32;
typedef __attribute__((ext_vector_type(8))) short short8;
typedef __attribute__((ext_vector_type(4))) float f32x4;

__device__ __forceinline__ u16 f2bf(float f) {
  union { float f; unsigned u; } v;
  v.f = f;
  unsigned r = (v.u + 0x7fffu + ((v.u >> 16) & 1u)) >> 16;  // RNE
  return (u16)r;
}
__device__ __forceinline__ float uasf(u32 u) {
  union { u32 u; float f; } v;
  v.u = u;
  return v.f;
}
// pack 2 fp32 -> 2 bf16 (RNE) in one instr
__device__ __forceinline__ u32 cvtpk(float lo, float hi) {
  u32 r;
  asm("v_cvt_pk_bf16_f32 %0, %1, %2" : "=v"(r) : "v"(lo), "v"(hi));
  return r;
}

// ---------------------------------------------------------------------------
// MFMA projection: xb[r][c] = bf16(relu(px[r][:] @ W[:][c] + b[c])), r<NP.
// ---------------------------------------------------------------------------
__global__ __launch_bounds__(256) void proj_mfma_kernel(
    const float* __restrict__ px, const float* __restrict__ W,
    const float* __restrict__ bias, u16* __restrict__ xb) {
  __shared__ u16 lA[2][128 * 32];  // 8 KB per buffer, bf16, swizzled
  const int t = threadIdx.x;
  const int l = t & 63;
  const int wid = t >> 6;
  const int row0 = blockIdx.x * 128;

  const int n0 = wid * 16 + (l & 15);
  const int kb = (l >> 4) * 8;
  short8 bf[12];
#pragma unroll
  for (int kt = 0; kt < 12; ++kt) {
    union { u32 p[4]; short8 s; } uu;
#pragma unroll
    for (int j = 0; j < 4; ++j) {
      const float lo = W[(size_t)(kt * 32 + kb + 2 * j) * 64 + n0];
      const float hi = W[(size_t)(kt * 32 + kb + 2 * j + 1) * 64 + n0];
      uu.p[j] = cvtpk(lo, hi);
    }
    bf[kt] = uu.s;
  }
  const float bv = bias[n0];

  f32x4 acc[8];
#pragma unroll
  for (int rt = 0; rt < 8; ++rt) {
    f32x4 z = {0.f, 0.f, 0.f, 0.f};
    acc[rt] = z;
  }

  const int fr_base = (((l & 15) * 64 + (l >> 4) * 16)) ^ ((l & 7) << 4);

  float4 sreg[4];
#pragma unroll
  for (int i = 0; i < 4; ++i) {
    const int qi = t + 256 * i;
    const int r = qi >> 3, q = qi & 7;
    const int grow = row0 + r;
    sreg[i] = (grow < NP) ? *reinterpret_cast<const float4*>(px + (size_t)grow * 384 + q * 4)
                          : make_float4(0.f, 0.f, 0.f, 0.f);
  }
#pragma unroll
  for (int i = 0; i < 4; ++i) {
    const int qi = t + 256 * i;
    const int r = qi >> 3, q = qi & 7;
    const int a16 = (((r * 64 + q * 8)) ^ ((r & 7) << 4)) >> 1;
    const u32 p0 = cvtpk(sreg[i].x, sreg[i].y);
    const u32 p1 = cvtpk(sreg[i].z, sreg[i].w);
    *reinterpret_cast<uint2*>(&lA[0][a16]) = make_uint2(p0, p1);
  }

#pragma unroll
  for (int kt = 0; kt < 12; ++kt) {
    const int cur = kt & 1;
    if (kt + 1 < 12) {
#pragma unroll
      for (int i = 0; i < 4; ++i) {
        const int qi = t + 256 * i;
        const int r = qi >> 3, q = qi & 7;
        const int grow = row0 + r;
        sreg[i] = (grow < NP)
                      ? *reinterpret_cast<const float4*>(px + (size_t)grow * 384 +
                                                         (kt + 1) * 32 + q * 4)
                      : make_float4(0.f, 0.f, 0.f, 0.f);
      }
    }
    __syncthreads();
#pragma unroll
    for (int rt = 0; rt < 8; ++rt) {
      const short8 af =
          *reinterpret_cast<const short8*>(&lA[cur][(fr_base + rt * 1024) >> 1]);
      acc[rt] = __builtin_amdgcn_mfma_f32_16x16x32_bf16(af, bf[kt], acc[rt], 0, 0, 0);
    }
    if (kt + 1 < 12) {
#pragma unroll
      for (int i = 0; i < 4; ++i) {
        const int qi = t + 256 * i;
        const int r = qi >> 3, q = qi & 7;
        const int a16 = (((r * 64 + q * 8)) ^ ((r & 7) << 4)) >> 1;
        const u32 p0 = cvtpk(sreg[i].x, sreg[i].y);
        const u32 p1 = cvtpk(sreg[i].z, sreg[i].w);
        *reinterpret_cast<uint2*>(&lA[cur ^ 1][a16]) = make_uint2(p0, p1);
      }
    }
  }

#pragma unroll
  for (int rt = 0; rt < 8; ++rt) {
#pragma unroll
    for (int r = 0; r < 4; ++r) {
      const int grow = row0 + rt * 16 + (l >> 4) * 4 + r;
      if (grow < NP)
        xb[(size_t)grow * 64 + n0] = f2bf(fmaxf(acc[rt][r] + bv, 0.f));
    }
  }
}

// ---------------------------------------------------------------------------
// Fused fp32->bf16 conversion of all 4 embedding tables into xb.
// ---------------------------------------------------------------------------
__global__ void cvt_emb_kernel(const float* __restrict__ ue, const float* __restrict__ be,
                               const float* __restrict__ ce, const float* __restrict__ se,
                               u16* __restrict__ xb) {
  const int i = blockIdx.x * 256 + threadIdx.x;
  const int totalQ = (NU + NBR + NCAT + NSH) * 16;
  if (i >= totalQ) return;
  const int row = i >> 4, q = i & 15;
  const float* src;
  int lrow;
  if (row < NU) {
    src = ue; lrow = row;
  } else if (row < NU + NBR) {
    src = be; lrow = row - NU;
  } else if (row < NU + NBR + NCAT) {
    src = ce; lrow = row - NU - NBR;
  } else {
    src = se; lrow = row - NU - NBR - NCAT;
  }
  const float4 v = reinterpret_cast<const float4*>(src)[(size_t)lrow * 16 + q];
  ushort4 o;
  o.x = f2bf(v.x);
  o.y = f2bf(v.y);
  o.z = f2bf(v.z);
  o.w = f2bf(v.w);
  reinterpret_cast<ushort4*>(xb + (size_t)(OFF_U + row) * 64)[q] = o;
}

// ---------------------------------------------------------------------------
// Directed-entry decode shared by degree & passA. i in [0, 2*nE).
// ---------------------------------------------------------------------------
__device__ __forceinline__ void decode_edge(
    int i, const int* pbs, const int* pbd, const int* pcs, const int* pcd,
    const int* pss, const int* psd, const int* ups, const int* upd,
    int nPB, int nPC, int nPS, int& a, int& b) {
  const int d = i & 1;
  int eu = i >> 1;
  int a0, b0;
  if (eu < nPB) {
    a0 = pbs[eu]; b0 = pbd[eu] + OFF_B;
  } else {
    eu -= nPB;
    if (eu < nPC) {
      a0 = pcs[eu]; b0 = pcd[eu] + OFF_C;
    } else {
      eu -= nPC;
      if (eu < nPS) {
        a0 = pss[eu]; b0 = psd[eu] + OFF_S;
      } else {
        eu -= nPS;
        a0 = ups[eu] + OFF_U; b0 = upd[eu];
      }
    }
  }
  a = d ? b0 : a0;
  b = d ? a0 : b0;
}

// Degree count (per directed entry).
__global__ void degree_all_kernel(const int* __restrict__ pbs, const int* __restrict__ pbd,
                                  const int* __restrict__ pcs, const int* __restrict__ pcd,
                                  const int* __restrict__ pss, const int* __restrict__ psd,
                                  const int* __restrict__ ups, const int* __restrict__ upd,
                                  int nPB, int nPC, int nPS, int nD, int* __restrict__ cnt) {
  const int i = blockIdx.x * 256 + threadIdx.x;
  if (i >= nD) return;
  int a, b;
  decode_edge(i, pbs, pbd, pcs, pcd, pss, psd, ups, upd, nPB, nPC, nPS, a, b);
  atomicAdd(&cnt[a], 1);
}

// 3-kernel exclusive scan cnt[NN] -> rowptr[NN+1]
__global__ __launch_bounds__(256) void scan1_kernel(const int* __restrict__ cnt,
                                                    int* __restrict__ blockSums, int n) {
  __shared__ int sdata[256];
  const int base = blockIdx.x * 1024;
  int s = 0;
  for (int i = threadIdx.x; i < 1024; i += 256) {
    int idx = base + i;
    if (idx < n) s += cnt[idx];
  }
  sdata[threadIdx.x] = s;
  __syncthreads();
  for (int off = 128; off > 0; off >>= 1) {
    if (threadIdx.x < off) sdata[threadIdx.x] += sdata[threadIdx.x + off];
    __syncthreads();
  }
  if (threadIdx.x == 0) blockSums[blockIdx.x] = sdata[0];
}

__global__ __launch_bounds__(512) void scan2_kernel(int* __restrict__ blockSums, int nb) {
  __shared__ int sd[512];
  const int t = threadIdx.x;
  const int v = (t < nb) ? blockSums[t] : 0;
  sd[t] = v;
  __syncthreads();
  for (int off = 1; off < 512; off <<= 1) {
    int add = (t >= off) ? sd[t - off] : 0;
    __syncthreads();
    sd[t] += add;
    __syncthreads();
  }
  if (t < nb) blockSums[t] = sd[t] - v;  // exclusive
}

__global__ __launch_bounds__(256) void scan3_kernel(const int* __restrict__ cnt,
                                                    const int* __restrict__ blockSums,
                                                    int* __restrict__ rowptr, int n) {
  __shared__ int wsum[4];
  const int base = blockIdx.x * 1024;
  const int t = threadIdx.x, lane = t & 63, wid = t >> 6;
  const int idx0 = base + t * 4;
  int v[4];
#pragma unroll
  for (int j = 0; j < 4; ++j) {
    int idx = idx0 + j;
    v[j] = (idx < n) ? cnt[idx] : 0;
  }
  const int s = v[0] + v[1] + v[2] + v[3];
  int incl = s;
  for (int off = 1; off < 64; off <<= 1) {
    int tt = __shfl_up(incl, off);
    if (lane >= off) incl += tt;
  }
  if (lane == 63) wsum[wid] = incl;
  __syncthreads();
  int wOff = 0;
#pragma unroll
  for (int w = 0; w < 4; ++w)
    if (w < wid) wOff += wsum[w];
  int run = blockSums[blockIdx.x] + wOff + (incl - s);
#pragma unroll
  for (int j = 0; j < 4; ++j) {
    int idx = idx0 + j;
    if (idx < n) {
      rowptr[idx] = run;
      run += v[j];
      if (idx == n - 1) rowptr[n] = run;
    }
  }
}

// init bin cursors + overflow counter
__global__ void init_bins_kernel(int* __restrict__ gcur, int* __restrict__ ovCnt) {
  const int t = threadIdx.x;
  if (t < MAXBINS) gcur[t * 16] = t * BIN_SZ;  // padded: one counter per 64B line
  if (t == 0) *ovCnt = 0;
}

// ---------------------------------------------------------------------------
// Pass A: per directed entry compute (pos = rowptr[a]+cursor[a]++, b), append
// record to its bin (bin = pos / BIN_SZ) via LDS staging (chunked flushes).
// Over-CAP records spill to the global overflow list.
// ---------------------------------------------------------------------------
__global__ __launch_bounds__(256) void build_passA_kernel(
    const int* __restrict__ pbs, const int* __restrict__ pbd,
    const int* __restrict__ pcs, const int* __restrict__ pcd,
    const int* __restrict__ pss, const int* __restrict__ psd,
    const int* __restrict__ ups, const int* __restrict__ upd,
    int nPB, int nPC, int nPS, int nD, const int* __restrict__ rowptr,
    int* __restrict__ cursor, uint2* __restrict__ gbuf, int* __restrict__ gcur,
    uint2* __restrict__ ovBuf, int* __restrict__ ovCnt) {
  __shared__ int lcnt[MAXBINS];
  __shared__ uint2 lbuf[MAXBINS][CAP];
  const int t = threadIdx.x;
  const int G = gridDim.x;

  if (t < MAXBINS) lcnt[t] = 0;
  __syncthreads();

  for (int base = blockIdx.x * 1024; base < nD; base += G * 1024) {
#pragma unroll
    for (int j = 0; j < 4; ++j) {
      const int i = base + j * 256 + t;
      if (i < nD) {
        int a, b;
        decode_edge(i, pbs, pbd, pcs, pcd, pss, psd, ups, upd, nPB, nPC, nPS, a, b);
        const int pa = atomicAdd(&cursor[a], 1);
        const u32 pos = (u32)(rowptr[a] + pa);
        const int bin = pos / BIN_SZ;
        const uint2 rec = make_uint2(pos, (u32)b);
        const int slot = atomicAdd(&lcnt[bin], 1);
        if (slot < CAP) {
          lbuf[bin][slot] = rec;
        } else {
          const int o = atomicAdd(ovCnt, 1);
          if (o < OVCAP) ovBuf[o] = rec;
        }
      }
    }
    __syncthreads();
    // drain: thread t owns bin t
    if (t < MAXBINS) {
      int c = lcnt[t];
      if (c > 0) {
        c = (c < CAP) ? c : CAP;
        const int gb = atomicAdd(&gcur[t * 16], c);
        for (int k = 0; k < c; ++k) gbuf[gb + k] = lbuf[t][k];
      }
      lcnt[t] = 0;
    }
    __syncthreads();
  }
}

// Pass B: one WG per bin; stream ONLY the records passA deposited
// (end = gcur[bin], NOT the full bin range — spilled slots are holes).
__global__ __launch_bounds__(512) void build_passB_kernel(
    const uint2* __restrict__ gbuf, const int* __restrict__ gcur,
    int* __restrict__ eidx) {
  const int b = blockIdx.x;
  const int start = b * BIN_SZ;
  const int end = gcur[b * 16];  // final fill level of this bin
  for (int i = start + threadIdx.x; i < end; i += 512) {
    const uint2 r = gbuf[i];
    eidx[r.x] = (int)r.y;
  }
}

// Overflow records (LDS-slot spills): direct scatter.
__global__ void build_overflow_kernel(const uint2* __restrict__ ovBuf,
                                      const int* __restrict__ ovCnt,
                                      int* __restrict__ eidx) {
  int n = *ovCnt;
  n = (n < OVCAP) ? n : OVCAP;
  for (int i = blockIdx.x * 256 + threadIdx.x; i < n; i += gridDim.x * 256) {
    const uint2 r = ovBuf[i];
    eidx[r.x] = (int)r.y;
  }
}

// ---------------------------------------------------------------------------
// Gather-mean: sout[node][:] = bf16(mean_{j in N(node)} xin[j][:]).
// ---------------------------------------------------------------------------
__global__ __launch_bounds__(256) void gather_mean_kernel(
    const int* __restrict__ rowptr, const int* __restrict__ eidx,
    const u32* __restrict__ xin, u32* __restrict__ sout) {
  const int lane = threadIdx.x & 63;
  const int q = lane & 31;
  const int h = lane >> 5;
  const int wid0 = blockIdx.x * 4 + (threadIdx.x >> 6);
  const int nW = gridDim.x * 4;
  for (int node = wid0; node < NN; node += nW) {
    const int r0 = rowptr[node], r1 = rowptr[node + 1];
    float sl = 0.f, sh = 0.f;
    for (int e = r0; e < r1; e += 8) {
      int nj[4];
#pragma unroll
      for (int j = 0; j < 4; ++j) {
        const int ee = e + 2 * j + h;
        const int ec = (ee < r1 - 1) ? ee : (r1 - 1);
        nj[j] = eidx[ec];
      }
      u32 rv[4];
#pragma unroll
      for (int j = 0; j < 4; ++j) {
        u32 r = xin[(size_t)nj[j] * 32 + q];
        rv[j] = (e + 2 * j + h < r1) ? r : 0u;
      }
#pragma unroll
      for (int j = 0; j < 4; ++j) {
        sl += uasf(rv[j] << 16);
        sh += uasf(rv[j] & 0xffff0000u);
      }
    }
    sl += __shfl_xor(sl, 32);
    sh += __shfl_xor(sh, 32);
    if (h == 0) {
      const int deg = r1 - r0;
      const float inv = (deg > 0) ? (1.f / (float)deg) : 1.f;
      const u32 o = (u32)f2bf(sl * inv) | ((u32)f2bf(sh * inv) << 16);
      sout[(size_t)node * 32 + q] = o;
    }
  }
}

// ---------------------------------------------------------------------------
// Dense layer GEMM: out = act(S @ Wl + bl + X @ Wr), S,X bf16 [NN][64].
// ---------------------------------------------------------------------------
template <int DOUT, bool RELU>
__global__ __launch_bounds__(256) void layer_gemm_kernel(
    const u32* __restrict__ S, const u32* __restrict__ X,
    const float* __restrict__ Wl, const float* __restrict__ bl,
    const float* __restrict__ Wr, void* __restrict__ outv) {
  constexpr int NC = DOUT / 4;
  constexpr int NR = 256 / NC;
  constexpr int R = 128 / NR;
  __shared__ __align__(16) u32 lS[128 * 32];
  __shared__ __align__(16) u32 lX[128 * 32];
  __shared__ __align__(16) float lWl[64 * DOUT];
  __shared__ __align__(16) float lWr[64 * DOUT];
  const int t = threadIdx.x;
  const int row0 = blockIdx.x * 128;

#pragma unroll
  for (int i = 0; i < (64 * DOUT) / 1024; ++i) {
    const int idx = i * 256 + t;
    reinterpret_cast<float4*>(lWl)[idx] = reinterpret_cast<const float4*>(Wl)[idx];
    reinterpret_cast<float4*>(lWr)[idx] = reinterpret_cast<const float4*>(Wr)[idx];
  }
#pragma unroll
  for (int i = 0; i < 4; ++i) {
    const int idx = i * 256 + t;
    const int r = idx >> 3, c = idx & 7;
    uint4 vs = make_uint4(0u, 0u, 0u, 0u), vx = vs;
    if (row0 + r < NN) {
      vs = reinterpret_cast<const uint4*>(S)[(size_t)(row0 + r) * 8 + c];
      vx = reinterpret_cast<const uint4*>(X)[(size_t)(row0 + r) * 8 + c];
    }
    reinterpret_cast<uint4*>(lS)[idx] = vs;
    reinterpret_cast<uint4*>(lX)[idx] = vx;
  }
  __syncthreads();

  const int cg = t % NC, rg = t / NC;
  const int c0 = cg * 4;
  float acc[R][4];
#pragma unroll
  for (int r = 0; r < R; ++r)
#pragma unroll
    for (int c = 0; c < 4; ++c) acc[r][c] = 0.f;

  for (int kq = 0; kq < 16; ++kq) {
    float4 wl4[4], wr4[4];
#pragma unroll
    for (int j = 0; j < 4; ++j) {
      wl4[j] = *reinterpret_cast<const float4*>(&lWl[(kq * 4 + j) * DOUT + c0]);
      wr4[j] = *reinterpret_cast<const float4*>(&lWr[(kq * 4 + j) * DOUT + c0]);
    }
#pragma unroll
    for (int r = 0; r < R; ++r) {
      const int row = rg * R + r;
      const uint2 sv = *reinterpret_cast<const uint2*>(&lS[row * 32 + kq * 2]);
      const uint2 xv = *reinterpret_cast<const uint2*>(&lX[row * 32 + kq * 2]);
      const float sf[4] = {uasf(sv.x << 16), uasf(sv.x & 0xffff0000u),
                           uasf(sv.y << 16), uasf(sv.y & 0xffff0000u)};
      const float xf[4] = {uasf(xv.x << 16), uasf(xv.x & 0xffff0000u),
                           uasf(xv.y << 16), uasf(xv.y & 0xffff0000u)};
#pragma unroll
      for (int j = 0; j < 4; ++j) {
        acc[r][0] = fmaf(sf[j], wl4[j].x, acc[r][0]);
        acc[r][1] = fmaf(sf[j], wl4[j].y, acc[r][1]);
        acc[r][2] = fmaf(sf[j], wl4[j].z, acc[r][2]);
        acc[r][3] = fmaf(sf[j], wl4[j].w, acc[r][3]);
        acc[r][0] = fmaf(xf[j], wr4[j].x, acc[r][0]);
        acc[r][1] = fmaf(xf[j], wr4[j].y, acc[r][1]);
        acc[r][2] = fmaf(xf[j], wr4[j].z, acc[r][2]);
        acc[r][3] = fmaf(xf[j], wr4[j].w, acc[r][3]);
      }
    }
  }

  const float b0 = bl[c0 + 0], b1 = bl[c0 + 1], b2 = bl[c0 + 2], b3 = bl[c0 + 3];
#pragma unroll
  for (int r = 0; r < R; ++r) {
    const int grow = row0 + rg * R + r;
    if (grow < NN) {
      float o0 = acc[r][0] + b0, o1 = acc[r][1] + b1, o2 = acc[r][2] + b2, o3 = acc[r][3] + b3;
      if (RELU) {
        o0 = fmaxf(o0, 0.f); o1 = fmaxf(o1, 0.f); o2 = fmaxf(o2, 0.f); o3 = fmaxf(o3, 0.f);
      }
      if (DOUT == 64) {
        ushort4 o;
        o.x = f2bf(o0); o.y = f2bf(o1); o.z = f2bf(o2); o.w = f2bf(o3);
        *reinterpret_cast<ushort4*>((u16*)outv + (size_t)grow * 64 + c0) = o;
      } else {
        float4 o = make_float4(o0, o1, o2, o3);
        *reinterpret_cast<float4*>((float*)outv + (size_t)grow * 32 + c0) = o;
      }
    }
  }
}

// ---------------------------------------------------------------------------
extern "C" void kernel_launch(void* const* d_in, const int* in_sizes, int n_in,
                              void* d_out, int out_size, void* d_ws, size_t ws_size,
                              hipStream_t stream) {
  const float* product_x = (const float*)d_in[0];
  const float* user_emb = (const float*)d_in[1];
  const float* brand_emb = (const float*)d_in[2];
  const float* cat_emb = (const float*)d_in[3];
  const float* shop_emb = (const float*)d_in[4];
  const float* proj_W = (const float*)d_in[5];
  const float* proj_b = (const float*)d_in[6];
  const float* c1_Wl = (const float*)d_in[7];
  const float* c1_bl = (const float*)d_in[8];
  const float* c1_Wr = (const float*)d_in[9];
  const float* c2_Wl = (const float*)d_in[10];
  const float* c2_bl = (const float*)d_in[11];
  const float* c2_Wr = (const float*)d_in[12];
  const int* pb_src = (const int*)d_in[13];
  const int* pb_dst = (const int*)d_in[14];
  const int* pc_src = (const int*)d_in[15];
  const int* pc_dst = (const int*)d_in[16];
  const int* ps_src = (const int*)d_in[17];
  const int* ps_dst = (const int*)d_in[18];
  const int* up_src = (const int*)d_in[19];
  const int* up_dst = (const int*)d_in[20];
  const int nPB = in_sizes[13], nPC = in_sizes[15], nPS = in_sizes[17], nUP = in_sizes[19];
  const int nE = nPB + nPC + nPS + nUP;
  const int nD = 2 * nE;
  const int nbins = (nD + BIN_SZ - 1) / BIN_SZ;  // 55 for default sizes

  // workspace layout (bf16 tables as u16/u32 views)
  u16* xb = (u16*)d_ws;                          // [NN*64] bf16
  u16* out1 = xb + (size_t)NN * 64;              // [NN*64] bf16
  u16* sbuf = out1 + (size_t)NN * 64;            // [NN*64] bf16 (reused both layers)
  int* eidx = (int*)(sbuf + (size_t)NN * 64);    // [nD]
  int* rowptr = eidx + nD;                       // [NN+1]
  int* cnt = rowptr + (NN + 1);                  // [NN]
  int* cursor = cnt + NN;                        // [NN]
  int* blockSums = cursor + NN;                  // [512]
  int* gcur = blockSums + 512;                   // [MAXBINS*16] padded
  int* ovCnt = gcur + MAXBINS * 16;              // [1]
  // aliased scratch (dead before their regions' first real write):
  uint2* gbuf = (uint2*)sbuf;   // [nD] 28.8MB <= 39.4MB; dead before gather1 writes sbuf
  uint2* ovBuf = (uint2*)out1;  // [OVCAP] 8MB; dead before gemm1 writes out1

  hipMemsetAsync(cnt, 0, NN * sizeof(int), stream);
  hipMemsetAsync(cursor, 0, NN * sizeof(int), stream);

  degree_all_kernel<<<(nD + 255) / 256, 256, 0, stream>>>(
      pb_src, pb_dst, pc_src, pc_dst, ps_src, ps_dst, up_src, up_dst, nPB, nPC, nPS, nD, cnt);

  const int nb = (NN + 1023) / 1024;  // 301
  scan1_kernel<<<nb, 256, 0, stream>>>(cnt, blockSums, NN);
  scan2_kernel<<<1, 512, 0, stream>>>(blockSums, nb);
  scan3_kernel<<<nb, 256, 0, stream>>>(cnt, blockSums, rowptr, NN);

  init_bins_kernel<<<1, 128, 0, stream>>>(gcur, ovCnt);
  build_passA_kernel<<<440, 256, 0, stream>>>(
      pb_src, pb_dst, pc_src, pc_dst, ps_src, ps_dst, up_src, up_dst, nPB, nPC, nPS, nD,
      rowptr, cursor, gbuf, gcur, ovBuf, ovCnt);
  build_passB_kernel<<<nbins, 512, 0, stream>>>(gbuf, gcur, eidx);
  build_overflow_kernel<<<16, 256, 0, stream>>>(ovBuf, ovCnt, eidx);

  proj_mfma_kernel<<<(NP + 127) / 128, 256, 0, stream>>>(product_x, proj_W, proj_b, xb);
  cvt_emb_kernel<<<((NU + NBR + NCAT + NSH) * 16 + 255) / 256, 256, 0, stream>>>(
      user_emb, brand_emb, cat_emb, shop_emb, xb);

  // Layer 1
  gather_mean_kernel<<<4096, 256, 0, stream>>>(rowptr, eidx, (const u32*)xb, (u32*)sbuf);
  layer_gemm_kernel<64, true><<<(NN + 127) / 128, 256, 0, stream>>>(
      (const u32*)sbuf, (const u32*)xb, c1_Wl, c1_bl, c1_Wr, out1);
  // Layer 2
  gather_mean_kernel<<<4096, 256, 0, stream>>>(rowptr, eidx, (const u32*)out1, (u32*)sbuf);
  layer_gemm_kernel<32, false><<<(NN + 127) / 128, 256, 0, stream>>>(
      (const u32*)sbuf, (const u32*)out1, c2_Wl, c2_bl, c2_Wr, d_out);
}

// Round 7
// 1005.423 us; speedup vs baseline: 1.1442x; 1.1442x over previous
//
#include <hip/hip_runtime.h>

#define NP 200000
#define NU 100000
#define NBR 5000
#define NCAT 2000
#define NSH 1000
#define NN (NP + NU + NBR + NCAT + NSH) /* 308000 */
#define OFF_U NP
#define OFF_B (NP + NU)
#define OFF_C (NP + NU + NBR)
#define OFF_S (NP + NU + NBR + NCAT)

#define BIN_SZ 65536 /* records per bin (256KB eidx window) */
#define MAXBINS 64
#define BATCH 1024

typedef unsigned short u16;
typedef unsigned int u32;
typedef __attribute__((ext_vector_type(8))) short short8;
typedef __attribute__((ext_vector_type(4))) float f32x4;

__device__ __forceinline__ u16 f2bf(float f) {
  union { float f; unsigned u; } v;
  v.f = f;
  unsigned r = (v.u + 0x7fffu + ((v.u >> 16) & 1u)) >> 16;  // RNE
  return (u16)r;
}
__device__ __forceinline__ float uasf(u32 u) {
  union { u32 u; float f; } v;
  v.u = u;
  return v.f;
}
// pack 2 fp32 -> 2 bf16 (RNE) in one instr
__device__ __forceinline__ u32 cvtpk(float lo, float hi) {
  u32 r;
  asm("v_cvt_pk_bf16_f32 %0, %1, %2" : "=v"(r) : "v"(lo), "v"(hi));
  return r;
}

// ---------------------------------------------------------------------------
// MFMA projection: xb[r][c] = bf16(relu(px[r][:] @ W[:][c] + b[c])), r<NP.
// ---------------------------------------------------------------------------
__global__ __launch_bounds__(256) void proj_mfma_kernel(
    const float* __restrict__ px, const float* __restrict__ W,
    const float* __restrict__ bias, u16* __restrict__ xb) {
  __shared__ u16 lA[2][128 * 32];  // 8 KB per buffer, bf16, swizzled
  const int t = threadIdx.x;
  const int l = t & 63;
  const int wid = t >> 6;
  const int row0 = blockIdx.x * 128;

  const int n0 = wid * 16 + (l & 15);
  const int kb = (l >> 4) * 8;
  short8 bf[12];
#pragma unroll
  for (int kt = 0; kt < 12; ++kt) {
    union { u32 p[4]; short8 s; } uu;
#pragma unroll
    for (int j = 0; j < 4; ++j) {
      const float lo = W[(size_t)(kt * 32 + kb + 2 * j) * 64 + n0];
      const float hi = W[(size_t)(kt * 32 + kb + 2 * j + 1) * 64 + n0];
      uu.p[j] = cvtpk(lo, hi);
    }
    bf[kt] = uu.s;
  }
  const float bv = bias[n0];

  f32x4 acc[8];
#pragma unroll
  for (int rt = 0; rt < 8; ++rt) {
    f32x4 z = {0.f, 0.f, 0.f, 0.f};
    acc[rt] = z;
  }

  const int fr_base = (((l & 15) * 64 + (l >> 4) * 16)) ^ ((l & 7) << 4);

  float4 sreg[4];
#pragma unroll
  for (int i = 0; i < 4; ++i) {
    const int qi = t + 256 * i;
    const int r = qi >> 3, q = qi & 7;
    const int grow = row0 + r;
    sreg[i] = (grow < NP) ? *reinterpret_cast<const float4*>(px + (size_t)grow * 384 + q * 4)
                          : make_float4(0.f, 0.f, 0.f, 0.f);
  }
#pragma unroll
  for (int i = 0; i < 4; ++i) {
    const int qi = t + 256 * i;
    const int r = qi >> 3, q = qi & 7;
    const int a16 = (((r * 64 + q * 8)) ^ ((r & 7) << 4)) >> 1;
    const u32 p0 = cvtpk(sreg[i].x, sreg[i].y);
    const u32 p1 = cvtpk(sreg[i].z, sreg[i].w);
    *reinterpret_cast<uint2*>(&lA[0][a16]) = make_uint2(p0, p1);
  }

#pragma unroll
  for (int kt = 0; kt < 12; ++kt) {
    const int cur = kt & 1;
    if (kt + 1 < 12) {
#pragma unroll
      for (int i = 0; i < 4; ++i) {
        const int qi = t + 256 * i;
        const int r = qi >> 3, q = qi & 7;
        const int grow = row0 + r;
        sreg[i] = (grow < NP)
                      ? *reinterpret_cast<const float4*>(px + (size_t)grow * 384 +
                                                         (kt + 1) * 32 + q * 4)
                      : make_float4(0.f, 0.f, 0.f, 0.f);
      }
    }
    __syncthreads();
#pragma unroll
    for (int rt = 0; rt < 8; ++rt) {
      const short8 af =
          *reinterpret_cast<const short8*>(&lA[cur][(fr_base + rt * 1024) >> 1]);
      acc[rt] = __builtin_amdgcn_mfma_f32_16x16x32_bf16(af, bf[kt], acc[rt], 0, 0, 0);
    }
    if (kt + 1 < 12) {
#pragma unroll
      for (int i = 0; i < 4; ++i) {
        const int qi = t + 256 * i;
        const int r = qi >> 3, q = qi & 7;
        const int a16 = (((r * 64 + q * 8)) ^ ((r & 7) << 4)) >> 1;
        const u32 p0 = cvtpk(sreg[i].x, sreg[i].y);
        const u32 p1 = cvtpk(sreg[i].z, sreg[i].w);
        *reinterpret_cast<uint2*>(&lA[cur ^ 1][a16]) = make_uint2(p0, p1);
      }
    }
  }

#pragma unroll
  for (int rt = 0; rt < 8; ++rt) {
#pragma unroll
    for (int r = 0; r < 4; ++r) {
      const int grow = row0 + rt * 16 + (l >> 4) * 4 + r;
      if (grow < NP)
        xb[(size_t)grow * 64 + n0] = f2bf(fmaxf(acc[rt][r] + bv, 0.f));
    }
  }
}

// ---------------------------------------------------------------------------
// Fused fp32->bf16 conversion of all 4 embedding tables into xb.
// ---------------------------------------------------------------------------
__global__ void cvt_emb_kernel(const float* __restrict__ ue, const float* __restrict__ be,
                               const float* __restrict__ ce, const float* __restrict__ se,
                               u16* __restrict__ xb) {
  const int i = blockIdx.x * 256 + threadIdx.x;
  const int totalQ = (NU + NBR + NCAT + NSH) * 16;
  if (i >= totalQ) return;
  const int row = i >> 4, q = i & 15;
  const float* src;
  int lrow;
  if (row < NU) {
    src = ue; lrow = row;
  } else if (row < NU + NBR) {
    src = be; lrow = row - NU;
  } else if (row < NU + NBR + NCAT) {
    src = ce; lrow = row - NU - NBR;
  } else {
    src = se; lrow = row - NU - NBR - NCAT;
  }
  const float4 v = reinterpret_cast<const float4*>(src)[(size_t)lrow * 16 + q];
  ushort4 o;
  o.x = f2bf(v.x);
  o.y = f2bf(v.y);
  o.z = f2bf(v.z);
  o.w = f2bf(v.w);
  reinterpret_cast<ushort4*>(xb + (size_t)(OFF_U + row) * 64)[q] = o;
}

// ---------------------------------------------------------------------------
// Directed-entry decode shared by degree & passA. i in [0, 2*nE).
// ---------------------------------------------------------------------------
__device__ __forceinline__ void decode_edge(
    int i, const int* pbs, const int* pbd, const int* pcs, const int* pcd,
    const int* pss, const int* psd, const int* ups, const int* upd,
    int nPB, int nPC, int nPS, int& a, int& b) {
  const int d = i & 1;
  int eu = i >> 1;
  int a0, b0;
  if (eu < nPB) {
    a0 = pbs[eu]; b0 = pbd[eu] + OFF_B;
  } else {
    eu -= nPB;
    if (eu < nPC) {
      a0 = pcs[eu]; b0 = pcd[eu] + OFF_C;
    } else {
      eu -= nPC;
      if (eu < nPS) {
        a0 = pss[eu]; b0 = psd[eu] + OFF_S;
      } else {
        eu -= nPS;
        a0 = ups[eu] + OFF_U; b0 = upd[eu];
      }
    }
  }
  a = d ? b0 : a0;
  b = d ? a0 : b0;
}

// Degree count (per directed entry).
__global__ void degree_all_kernel(const int* __restrict__ pbs, const int* __restrict__ pbd,
                                  const int* __restrict__ pcs, const int* __restrict__ pcd,
                                  const int* __restrict__ pss, const int* __restrict__ psd,
                                  const int* __restrict__ ups, const int* __restrict__ upd,
                                  int nPB, int nPC, int nPS, int nD, int* __restrict__ cnt) {
  const int i = blockIdx.x * 256 + threadIdx.x;
  if (i >= nD) return;
  int a, b;
  decode_edge(i, pbs, pbd, pcs, pcd, pss, psd, ups, upd, nPB, nPC, nPS, a, b);
  atomicAdd(&cnt[a], 1);
}

// 3-kernel exclusive scan cnt[NN] -> rowptr[NN+1]
__global__ __launch_bounds__(256) void scan1_kernel(const int* __restrict__ cnt,
                                                    int* __restrict__ blockSums, int n) {
  __shared__ int sdata[256];
  const int base = blockIdx.x * 1024;
  int s = 0;
  for (int i = threadIdx.x; i < 1024; i += 256) {
    int idx = base + i;
    if (idx < n) s += cnt[idx];
  }
  sdata[threadIdx.x] = s;
  __syncthreads();
  for (int off = 128; off > 0; off >>= 1) {
    if (threadIdx.x < off) sdata[threadIdx.x] += sdata[threadIdx.x + off];
    __syncthreads();
  }
  if (threadIdx.x == 0) blockSums[blockIdx.x] = sdata[0];
}

__global__ __launch_bounds__(512) void scan2_kernel(int* __restrict__ blockSums, int nb) {
  __shared__ int sd[512];
  const int t = threadIdx.x;
  const int v = (t < nb) ? blockSums[t] : 0;
  sd[t] = v;
  __syncthreads();
  for (int off = 1; off < 512; off <<= 1) {
    int add = (t >= off) ? sd[t - off] : 0;
    __syncthreads();
    sd[t] += add;
    __syncthreads();
  }
  if (t < nb) blockSums[t] = sd[t] - v;  // exclusive
}

__global__ __launch_bounds__(256) void scan3_kernel(const int* __restrict__ cnt,
                                                    const int* __restrict__ blockSums,
                                                    int* __restrict__ rowptr, int n) {
  __shared__ int wsum[4];
  const int base = blockIdx.x * 1024;
  const int t = threadIdx.x, lane = t & 63, wid = t >> 6;
  const int idx0 = base + t * 4;
  int v[4];
#pragma unroll
  for (int j = 0; j < 4; ++j) {
    int idx = idx0 + j;
    v[j] = (idx < n) ? cnt[idx] : 0;
  }
  const int s = v[0] + v[1] + v[2] + v[3];
  int incl = s;
  for (int off = 1; off < 64; off <<= 1) {
    int tt = __shfl_up(incl, off);
    if (lane >= off) incl += tt;
  }
  if (lane == 63) wsum[wid] = incl;
  __syncthreads();
  int wOff = 0;
#pragma unroll
  for (int w = 0; w < 4; ++w)
    if (w < wid) wOff += wsum[w];
  int run = blockSums[blockIdx.x] + wOff + (incl - s);
#pragma unroll
  for (int j = 0; j < 4; ++j) {
    int idx = idx0 + j;
    if (idx < n) {
      rowptr[idx] = run;
      run += v[j];
      if (idx == n - 1) rowptr[n] = run;
    }
  }
}

// init bin cursors
__global__ void init_bins_kernel(int* __restrict__ gcur) {
  const int t = threadIdx.x;
  if (t < MAXBINS) gcur[t * 16] = t * BIN_SZ;  // padded: one counter per 64B line
}

// ---------------------------------------------------------------------------
// Pass A v2: per directed entry compute (pos = cursor[a]++, b) where cursor is
// pre-initialized to rowptr. Batch of 1024 records per block-iteration:
// exact histogram (LDS atomics) -> wave-0 exclusive scan -> stage grouped by
// bin in one 8KB LDS buffer -> 256-thread cooperative coalesced drain.
// No spill path (histogram is exact).
// ---------------------------------------------------------------------------
__global__ __launch_bounds__(256) void build_passA_kernel(
    const int* __restrict__ pbs, const int* __restrict__ pbd,
    const int* __restrict__ pcs, const int* __restrict__ pcd,
    const int* __restrict__ pss, const int* __restrict__ psd,
    const int* __restrict__ ups, const int* __restrict__ upd,
    int nPB, int nPC, int nPS, int nD,
    int* __restrict__ cursor, uint2* __restrict__ gbuf, int* __restrict__ gcur) {
  __shared__ int lcnt[MAXBINS];
  __shared__ int loff[MAXBINS];
  __shared__ int gb[MAXBINS];
  __shared__ uint2 lbuf[BATCH];
  const int t = threadIdx.x;

  for (int base = blockIdx.x * BATCH; base < nD; base += gridDim.x * BATCH) {
    const int n = min(BATCH, nD - base);
    if (t < MAXBINS) lcnt[t] = 0;
    __syncthreads();

    u32 pos[4], bv[4];
    int bin[4], slot[4];
#pragma unroll
    for (int j = 0; j < 4; ++j) {
      const int i = base + j * 256 + t;
      bin[j] = -1;
      if (i < nD) {
        int a, b;
        decode_edge(i, pbs, pbd, pcs, pcd, pss, psd, ups, upd, nPB, nPC, nPS, a, b);
        const int p = atomicAdd(&cursor[a], 1);  // cursor pre-init = rowptr
        pos[j] = (u32)p;
        bv[j] = (u32)b;
        bin[j] = p >> 16;  // p / BIN_SZ
        slot[j] = atomicAdd(&lcnt[bin[j]], 1);
      }
    }
    __syncthreads();

    if (t < 64) {  // wave 0: exclusive scan over 64 bins + reserve global room
      const int v = lcnt[t];
      int incl = v;
      for (int off = 1; off < 64; off <<= 1) {
        const int u = __shfl_up(incl, off);
        if (t >= off) incl += u;
      }
      loff[t] = incl - v;
      if (v > 0) gb[t] = atomicAdd(&gcur[t * 16], v);
    }
    __syncthreads();

#pragma unroll
    for (int j = 0; j < 4; ++j)
      if (bin[j] >= 0) lbuf[loff[bin[j]] + slot[j]] = make_uint2(pos[j], bv[j]);
    __syncthreads();

    for (int i = t; i < n; i += 256) {  // parallel coalesced drain
      const uint2 r = lbuf[i];
      const int bb = r.x >> 16;
      gbuf[gb[bb] + (i - loff[bb])] = r;
    }
    // no barrier needed: next iter's lcnt zero + 2 barriers precede any
    // write to loff/gb/lbuf.
  }
}

// Pass B: one WG per bin; stream the records passA deposited (end = gcur),
// scatter into this bin's 256KB eidx window (L2-resident -> merged lines).
__global__ __launch_bounds__(512) void build_passB_kernel(
    const uint2* __restrict__ gbuf, const int* __restrict__ gcur,
    int* __restrict__ eidx) {
  const int b = blockIdx.x;
  const int start = b * BIN_SZ;
  const int end = gcur[b * 16];  // final fill level of this bin
  for (int i = start + threadIdx.x; i < end; i += 512) {
    const uint2 r = gbuf[i];
    eidx[r.x] = (int)r.y;
  }
}

// ---------------------------------------------------------------------------
// Gather-mean: sout[node][:] = bf16(mean_{j in N(node)} xin[j][:]).
// ---------------------------------------------------------------------------
__global__ __launch_bounds__(256) void gather_mean_kernel(
    const int* __restrict__ rowptr, const int* __restrict__ eidx,
    const u32* __restrict__ xin, u32* __restrict__ sout) {
  const int lane = threadIdx.x & 63;
  const int q = lane & 31;
  const int h = lane >> 5;
  const int wid0 = blockIdx.x * 4 + (threadIdx.x >> 6);
  const int nW = gridDim.x * 4;
  for (int node = wid0; node < NN; node += nW) {
    const int r0 = rowptr[node], r1 = rowptr[node + 1];
    float sl = 0.f, sh = 0.f;
    for (int e = r0; e < r1; e += 8) {
      int nj[4];
#pragma unroll
      for (int j = 0; j < 4; ++j) {
        const int ee = e + 2 * j + h;
        const int ec = (ee < r1 - 1) ? ee : (r1 - 1);
        nj[j] = eidx[ec];
      }
      u32 rv[4];
#pragma unroll
      for (int j = 0; j < 4; ++j) {
        u32 r = xin[(size_t)nj[j] * 32 + q];
        rv[j] = (e + 2 * j + h < r1) ? r : 0u;
      }
#pragma unroll
      for (int j = 0; j < 4; ++j) {
        sl += uasf(rv[j] << 16);
        sh += uasf(rv[j] & 0xffff0000u);
      }
    }
    sl += __shfl_xor(sl, 32);
    sh += __shfl_xor(sh, 32);
    if (h == 0) {
      const int deg = r1 - r0;
      const float inv = (deg > 0) ? (1.f / (float)deg) : 1.f;
      const u32 o = (u32)f2bf(sl * inv) | ((u32)f2bf(sh * inv) << 16);
      sout[(size_t)node * 32 + q] = o;
    }
  }
}

// ---------------------------------------------------------------------------
// Dense layer GEMM: out = act(S @ Wl + bl + X @ Wr), S,X bf16 [NN][64].
// ---------------------------------------------------------------------------
template <int DOUT, bool RELU>
__global__ __launch_bounds__(256) void layer_gemm_kernel(
    const u32* __restrict__ S, const u32* __restrict__ X,
    const float* __restrict__ Wl, const float* __restrict__ bl,
    const float* __restrict__ Wr, void* __restrict__ outv) {
  constexpr int NC = DOUT / 4;
  constexpr int NR = 256 / NC;
  constexpr int R = 128 / NR;
  __shared__ __align__(16) u32 lS[128 * 32];
  __shared__ __align__(16) u32 lX[128 * 32];
  __shared__ __align__(16) float lWl[64 * DOUT];
  __shared__ __align__(16) float lWr[64 * DOUT];
  const int t = threadIdx.x;
  const int row0 = blockIdx.x * 128;

#pragma unroll
  for (int i = 0; i < (64 * DOUT) / 1024; ++i) {
    const int idx = i * 256 + t;
    reinterpret_cast<float4*>(lWl)[idx] = reinterpret_cast<const float4*>(Wl)[idx];
    reinterpret_cast<float4*>(lWr)[idx] = reinterpret_cast<const float4*>(Wr)[idx];
  }
#pragma unroll
  for (int i = 0; i < 4; ++i) {
    const int idx = i * 256 + t;
    const int r = idx >> 3, c = idx & 7;
    uint4 vs = make_uint4(0u, 0u, 0u, 0u), vx = vs;
    if (row0 + r < NN) {
      vs = reinterpret_cast<const uint4*>(S)[(size_t)(row0 + r) * 8 + c];
      vx = reinterpret_cast<const uint4*>(X)[(size_t)(row0 + r) * 8 + c];
    }
    reinterpret_cast<uint4*>(lS)[idx] = vs;
    reinterpret_cast<uint4*>(lX)[idx] = vx;
  }
  __syncthreads();

  const int cg = t % NC, rg = t / NC;
  const int c0 = cg * 4;
  float acc[R][4];
#pragma unroll
  for (int r = 0; r < R; ++r)
#pragma unroll
    for (int c = 0; c < 4; ++c) acc[r][c] = 0.f;

  for (int kq = 0; kq < 16; ++kq) {
    float4 wl4[4], wr4[4];
#pragma unroll
    for (int j = 0; j < 4; ++j) {
      wl4[j] = *reinterpret_cast<const float4*>(&lWl[(kq * 4 + j) * DOUT + c0]);
      wr4[j] = *reinterpret_cast<const float4*>(&lWr[(kq * 4 + j) * DOUT + c0]);
    }
#pragma unroll
    for (int r = 0; r < R; ++r) {
      const int row = rg * R + r;
      const uint2 sv = *reinterpret_cast<const uint2*>(&lS[row * 32 + kq * 2]);
      const uint2 xv = *reinterpret_cast<const uint2*>(&lX[row * 32 + kq * 2]);
      const float sf[4] = {uasf(sv.x << 16), uasf(sv.x & 0xffff0000u),
                           uasf(sv.y << 16), uasf(sv.y & 0xffff0000u)};
      const float xf[4] = {uasf(xv.x << 16), uasf(xv.x & 0xffff0000u),
                           uasf(xv.y << 16), uasf(xv.y & 0xffff0000u)};
#pragma unroll
      for (int j = 0; j < 4; ++j) {
        acc[r][0] = fmaf(sf[j], wl4[j].x, acc[r][0]);
        acc[r][1] = fmaf(sf[j], wl4[j].y, acc[r][1]);
        acc[r][2] = fmaf(sf[j], wl4[j].z, acc[r][2]);
        acc[r][3] = fmaf(sf[j], wl4[j].w, acc[r][3]);
        acc[r][0] = fmaf(xf[j], wr4[j].x, acc[r][0]);
        acc[r][1] = fmaf(xf[j], wr4[j].y, acc[r][1]);
        acc[r][2] = fmaf(xf[j], wr4[j].z, acc[r][2]);
        acc[r][3] = fmaf(xf[j], wr4[j].w, acc[r][3]);
      }
    }
  }

  const float b0 = bl[c0 + 0], b1 = bl[c0 + 1], b2 = bl[c0 + 2], b3 = bl[c0 + 3];
#pragma unroll
  for (int r = 0; r < R; ++r) {
    const int grow = row0 + rg * R + r;
    if (grow < NN) {
      float o0 = acc[r][0] + b0, o1 = acc[r][1] + b1, o2 = acc[r][2] + b2, o3 = acc[r][3] + b3;
      if (RELU) {
        o0 = fmaxf(o0, 0.f); o1 = fmaxf(o1, 0.f); o2 = fmaxf(o2, 0.f); o3 = fmaxf(o3, 0.f);
      }
      if (DOUT == 64) {
        ushort4 o;
        o.x = f2bf(o0); o.y = f2bf(o1); o.z = f2bf(o2); o.w = f2bf(o3);
        *reinterpret_cast<ushort4*>((u16*)outv + (size_t)grow * 64 + c0) = o;
      } else {
        float4 o = make_float4(o0, o1, o2, o3);
        *reinterpret_cast<float4*>((float*)outv + (size_t)grow * 32 + c0) = o;
      }
    }
  }
}

// ---------------------------------------------------------------------------
extern "C" void kernel_launch(void* const* d_in, const int* in_sizes, int n_in,
                              void* d_out, int out_size, void* d_ws, size_t ws_size,
                              hipStream_t stream) {
  const float* product_x = (const float*)d_in[0];
  const float* user_emb = (const float*)d_in[1];
  const float* brand_emb = (const float*)d_in[2];
  const float* cat_emb = (const float*)d_in[3];
  const float* shop_emb = (const float*)d_in[4];
  const float* proj_W = (const float*)d_in[5];
  const float* proj_b = (const float*)d_in[6];
  const float* c1_Wl = (const float*)d_in[7];
  const float* c1_bl = (const float*)d_in[8];
  const float* c1_Wr = (const float*)d_in[9];
  const float* c2_Wl = (const float*)d_in[10];
  const float* c2_bl = (const float*)d_in[11];
  const float* c2_Wr = (const float*)d_in[12];
  const int* pb_src = (const int*)d_in[13];
  const int* pb_dst = (const int*)d_in[14];
  const int* pc_src = (const int*)d_in[15];
  const int* pc_dst = (const int*)d_in[16];
  const int* ps_src = (const int*)d_in[17];
  const int* ps_dst = (const int*)d_in[18];
  const int* up_src = (const int*)d_in[19];
  const int* up_dst = (const int*)d_in[20];
  const int nPB = in_sizes[13], nPC = in_sizes[15], nPS = in_sizes[17], nUP = in_sizes[19];
  const int nE = nPB + nPC + nPS + nUP;
  const int nD = 2 * nE;
  const int nbins = (nD + BIN_SZ - 1) / BIN_SZ;  // 55 for default sizes

  // workspace layout (bf16 tables as u16/u32 views)
  u16* xb = (u16*)d_ws;                          // [NN*64] bf16
  u16* out1 = xb + (size_t)NN * 64;              // [NN*64] bf16
  u16* sbuf = out1 + (size_t)NN * 64;            // [NN*64] bf16 (reused both layers)
  int* eidx = (int*)(sbuf + (size_t)NN * 64);    // [nD]
  int* rowptr = eidx + nD;                       // [NN+1]
  int* cnt = rowptr + (NN + 1);                  // [NN]
  int* cursor = cnt + NN;                        // [NN]
  int* blockSums = cursor + NN;                  // [512]
  int* gcur = blockSums + 512;                   // [MAXBINS*16] padded
  // aliased scratch (dead before the gather phase writes sbuf):
  uint2* gbuf = (uint2*)sbuf;  // [nD] 28.8MB <= 39.4MB

  hipMemsetAsync(cnt, 0, NN * sizeof(int), stream);

  degree_all_kernel<<<(nD + 255) / 256, 256, 0, stream>>>(
      pb_src, pb_dst, pc_src, pc_dst, ps_src, ps_dst, up_src, up_dst, nPB, nPC, nPS, nD, cnt);

  const int nb = (NN + 1023) / 1024;  // 301
  scan1_kernel<<<nb, 256, 0, stream>>>(cnt, blockSums, NN);
  scan2_kernel<<<1, 512, 0, stream>>>(blockSums, nb);
  scan3_kernel<<<nb, 256, 0, stream>>>(cnt, blockSums, rowptr, NN);

  // cursor <- rowptr (running write positions), then pos = cursor[a]++.
  hipMemcpyAsync(cursor, rowptr, NN * sizeof(int), hipMemcpyDeviceToDevice, stream);

  init_bins_kernel<<<1, 128, 0, stream>>>(gcur);
  {
    const int nBatches = (nD + BATCH - 1) / BATCH;
    const int grid = (nBatches < 1760) ? nBatches : 1760;
    build_passA_kernel<<<grid, 256, 0, stream>>>(
        pb_src, pb_dst, pc_src, pc_dst, ps_src, ps_dst, up_src, up_dst, nPB, nPC, nPS, nD,
        cursor, gbuf, gcur);
  }
  build_passB_kernel<<<nbins, 512, 0, stream>>>(gbuf, gcur, eidx);

  proj_mfma_kernel<<<(NP + 127) / 128, 256, 0, stream>>>(product_x, proj_W, proj_b, xb);
  cvt_emb_kernel<<<((NU + NBR + NCAT + NSH) * 16 + 255) / 256, 256, 0, stream>>>(
      user_emb, brand_emb, cat_emb, shop_emb, xb);

  // Layer 1
  gather_mean_kernel<<<4096, 256, 0, stream>>>(rowptr, eidx, (const u32*)xb, (u32*)sbuf);
  layer_gemm_kernel<64, true><<<(NN + 127) / 128, 256, 0, stream>>>(
      (const u32*)sbuf, (const u32*)xb, c1_Wl, c1_bl, c1_Wr, out1);
  // Layer 2
  gather_mean_kernel<<<4096, 256, 0, stream>>>(rowptr, eidx, (const u32*)out1, (u32*)sbuf);
  layer_gemm_kernel<32, false><<<(NN + 127) / 128, 256, 0, stream>>>(
      (const u32*)sbuf, (const u32*)out1, c2_Wl, c2_bl, c2_Wr, d_out);
}

// Round 8
// 985.035 us; speedup vs baseline: 1.1679x; 1.0207x over previous
//
#include <hip/hip_runtime.h>

#define NP 200000
#define NU 100000
#define NBR 5000
#define NCAT 2000
#define NSH 1000
#define NN (NP + NU + NBR + NCAT + NSH) /* 308000 */
#define OFF_U NP
#define OFF_B (NP + NU)
#define OFF_C (NP + NU + NBR)
#define OFF_S (NP + NU + NBR + NCAT)

#define BIN_SZ 65536 /* records per bin (256KB eidx window) */
#define MAXBINS 64

typedef unsigned short u16;
typedef unsigned int u32;
typedef __attribute__((ext_vector_type(8))) short short8;
typedef __attribute__((ext_vector_type(4))) float f32x4;

__device__ __forceinline__ u16 f2bf(float f) {
  union { float f; unsigned u; } v;
  v.f = f;
  unsigned r = (v.u + 0x7fffu + ((v.u >> 16) & 1u)) >> 16;  // RNE
  return (u16)r;
}
__device__ __forceinline__ float uasf(u32 u) {
  union { u32 u; float f; } v;
  v.u = u;
  return v.f;
}
// pack 2 fp32 -> 2 bf16 (RNE) in one instr
__device__ __forceinline__ u32 cvtpk(float lo, float hi) {
  u32 r;
  asm("v_cvt_pk_bf16_f32 %0, %1, %2" : "=v"(r) : "v"(lo), "v"(hi));
  return r;
}

// ---------------------------------------------------------------------------
// MFMA projection: xb[r][c] = bf16(relu(px[r][:] @ W[:][c] + b[c])), r<NP.
// ---------------------------------------------------------------------------
__global__ __launch_bounds__(256) void proj_mfma_kernel(
    const float* __restrict__ px, const float* __restrict__ W,
    const float* __restrict__ bias, u16* __restrict__ xb) {
  __shared__ u16 lA[2][128 * 32];  // 8 KB per buffer, bf16, swizzled
  const int t = threadIdx.x;
  const int l = t & 63;
  const int wid = t >> 6;
  const int row0 = blockIdx.x * 128;

  const int n0 = wid * 16 + (l & 15);
  const int kb = (l >> 4) * 8;
  short8 bf[12];
#pragma unroll
  for (int kt = 0; kt < 12; ++kt) {
    union { u32 p[4]; short8 s; } uu;
#pragma unroll
    for (int j = 0; j < 4; ++j) {
      const float lo = W[(size_t)(kt * 32 + kb + 2 * j) * 64 + n0];
      const float hi = W[(size_t)(kt * 32 + kb + 2 * j + 1) * 64 + n0];
      uu.p[j] = cvtpk(lo, hi);
    }
    bf[kt] = uu.s;
  }
  const float bv = bias[n0];

  f32x4 acc[8];
#pragma unroll
  for (int rt = 0; rt < 8; ++rt) {
    f32x4 z = {0.f, 0.f, 0.f, 0.f};
    acc[rt] = z;
  }

  const int fr_base = (((l & 15) * 64 + (l >> 4) * 16)) ^ ((l & 7) << 4);

  float4 sreg[4];
#pragma unroll
  for (int i = 0; i < 4; ++i) {
    const int qi = t + 256 * i;
    const int r = qi >> 3, q = qi & 7;
    const int grow = row0 + r;
    sreg[i] = (grow < NP) ? *reinterpret_cast<const float4*>(px + (size_t)grow * 384 + q * 4)
                          : make_float4(0.f, 0.f, 0.f, 0.f);
  }
#pragma unroll
  for (int i = 0; i < 4; ++i) {
    const int qi = t + 256 * i;
    const int r = qi >> 3, q = qi & 7;
    const int a16 = (((r * 64 + q * 8)) ^ ((r & 7) << 4)) >> 1;
    const u32 p0 = cvtpk(sreg[i].x, sreg[i].y);
    const u32 p1 = cvtpk(sreg[i].z, sreg[i].w);
    *reinterpret_cast<uint2*>(&lA[0][a16]) = make_uint2(p0, p1);
  }

#pragma unroll
  for (int kt = 0; kt < 12; ++kt) {
    const int cur = kt & 1;
    if (kt + 1 < 12) {
#pragma unroll
      for (int i = 0; i < 4; ++i) {
        const int qi = t + 256 * i;
        const int r = qi >> 3, q = qi & 7;
        const int grow = row0 + r;
        sreg[i] = (grow < NP)
                      ? *reinterpret_cast<const float4*>(px + (size_t)grow * 384 +
                                                         (kt + 1) * 32 + q * 4)
                      : make_float4(0.f, 0.f, 0.f, 0.f);
      }
    }
    __syncthreads();
#pragma unroll
    for (int rt = 0; rt < 8; ++rt) {
      const short8 af =
          *reinterpret_cast<const short8*>(&lA[cur][(fr_base + rt * 1024) >> 1]);
      acc[rt] = __builtin_amdgcn_mfma_f32_16x16x32_bf16(af, bf[kt], acc[rt], 0, 0, 0);
    }
    if (kt + 1 < 12) {
#pragma unroll
      for (int i = 0; i < 4; ++i) {
        const int qi = t + 256 * i;
        const int r = qi >> 3, q = qi & 7;
        const int a16 = (((r * 64 + q * 8)) ^ ((r & 7) << 4)) >> 1;
        const u32 p0 = cvtpk(sreg[i].x, sreg[i].y);
        const u32 p1 = cvtpk(sreg[i].z, sreg[i].w);
        *reinterpret_cast<uint2*>(&lA[cur ^ 1][a16]) = make_uint2(p0, p1);
      }
    }
  }

#pragma unroll
  for (int rt = 0; rt < 8; ++rt) {
#pragma unroll
    for (int r = 0; r < 4; ++r) {
      const int grow = row0 + rt * 16 + (l >> 4) * 4 + r;
      if (grow < NP)
        xb[(size_t)grow * 64 + n0] = f2bf(fmaxf(acc[rt][r] + bv, 0.f));
    }
  }
}

// ---------------------------------------------------------------------------
// Fused fp32->bf16 conversion of all 4 embedding tables into xb.
// ---------------------------------------------------------------------------
__global__ void cvt_emb_kernel(const float* __restrict__ ue, const float* __restrict__ be,
                               const float* __restrict__ ce, const float* __restrict__ se,
                               u16* __restrict__ xb) {
  const int i = blockIdx.x * 256 + threadIdx.x;
  const int totalQ = (NU + NBR + NCAT + NSH) * 16;
  if (i >= totalQ) return;
  const int row = i >> 4, q = i & 15;
  const float* src;
  int lrow;
  if (row < NU) {
    src = ue; lrow = row;
  } else if (row < NU + NBR) {
    src = be; lrow = row - NU;
  } else if (row < NU + NBR + NCAT) {
    src = ce; lrow = row - NU - NBR;
  } else {
    src = se; lrow = row - NU - NBR - NCAT;
  }
  const float4 v = reinterpret_cast<const float4*>(src)[(size_t)lrow * 16 + q];
  ushort4 o;
  o.x = f2bf(v.x);
  o.y = f2bf(v.y);
  o.z = f2bf(v.z);
  o.w = f2bf(v.w);
  reinterpret_cast<ushort4*>(xb + (size_t)(OFF_U + row) * 64)[q] = o;
}

// ---------------------------------------------------------------------------
// Directed-entry decode shared by degree & passA. i in [0, 2*nE).
// ---------------------------------------------------------------------------
__device__ __forceinline__ void decode_edge(
    int i, const int* pbs, const int* pbd, const int* pcs, const int* pcd,
    const int* pss, const int* psd, const int* ups, const int* upd,
    int nPB, int nPC, int nPS, int& a, int& b) {
  const int d = i & 1;
  int eu = i >> 1;
  int a0, b0;
  if (eu < nPB) {
    a0 = pbs[eu]; b0 = pbd[eu] + OFF_B;
  } else {
    eu -= nPB;
    if (eu < nPC) {
      a0 = pcs[eu]; b0 = pcd[eu] + OFF_C;
    } else {
      eu -= nPC;
      if (eu < nPS) {
        a0 = pss[eu]; b0 = psd[eu] + OFF_S;
      } else {
        eu -= nPS;
        a0 = ups[eu] + OFF_U; b0 = upd[eu];
      }
    }
  }
  a = d ? b0 : a0;
  b = d ? a0 : b0;
}

// Degree count (per directed entry).
__global__ void degree_all_kernel(const int* __restrict__ pbs, const int* __restrict__ pbd,
                                  const int* __restrict__ pcs, const int* __restrict__ pcd,
                                  const int* __restrict__ pss, const int* __restrict__ psd,
                                  const int* __restrict__ ups, const int* __restrict__ upd,
                                  int nPB, int nPC, int nPS, int nD, int* __restrict__ cnt) {
  const int i = blockIdx.x * 256 + threadIdx.x;
  if (i >= nD) return;
  int a, b;
  decode_edge(i, pbs, pbd, pcs, pcd, pss, psd, ups, upd, nPB, nPC, nPS, a, b);
  atomicAdd(&cnt[a], 1);
}

// 3-kernel exclusive scan cnt[NN] -> rowptr[NN+1]
__global__ __launch_bounds__(256) void scan1_kernel(const int* __restrict__ cnt,
                                                    int* __restrict__ blockSums, int n) {
  __shared__ int sdata[256];
  const int base = blockIdx.x * 1024;
  int s = 0;
  for (int i = threadIdx.x; i < 1024; i += 256) {
    int idx = base + i;
    if (idx < n) s += cnt[idx];
  }
  sdata[threadIdx.x] = s;
  __syncthreads();
  for (int off = 128; off > 0; off >>= 1) {
    if (threadIdx.x < off) sdata[threadIdx.x] += sdata[threadIdx.x + off];
    __syncthreads();
  }
  if (threadIdx.x == 0) blockSums[blockIdx.x] = sdata[0];
}

__global__ __launch_bounds__(512) void scan2_kernel(int* __restrict__ blockSums, int nb) {
  __shared__ int sd[512];
  const int t = threadIdx.x;
  const int v = (t < nb) ? blockSums[t] : 0;
  sd[t] = v;
  __syncthreads();
  for (int off = 1; off < 512; off <<= 1) {
    int add = (t >= off) ? sd[t - off] : 0;
    __syncthreads();
    sd[t] += add;
    __syncthreads();
  }
  if (t < nb) blockSums[t] = sd[t] - v;  // exclusive
}

__global__ __launch_bounds__(256) void scan3_kernel(const int* __restrict__ cnt,
                                                    const int* __restrict__ blockSums,
                                                    int* __restrict__ rowptr, int n) {
  __shared__ int wsum[4];
  const int base = blockIdx.x * 1024;
  const int t = threadIdx.x, lane = t & 63, wid = t >> 6;
  const int idx0 = base + t * 4;
  int v[4];
#pragma unroll
  for (int j = 0; j < 4; ++j) {
    int idx = idx0 + j;
    v[j] = (idx < n) ? cnt[idx] : 0;
  }
  const int s = v[0] + v[1] + v[2] + v[3];
  int incl = s;
  for (int off = 1; off < 64; off <<= 1) {
    int tt = __shfl_up(incl, off);
    if (lane >= off) incl += tt;
  }
  if (lane == 63) wsum[wid] = incl;
  __syncthreads();
  int wOff = 0;
#pragma unroll
  for (int w = 0; w < 4; ++w)
    if (w < wid) wOff += wsum[w];
  int run = blockSums[blockIdx.x] + wOff + (incl - s);
#pragma unroll
  for (int j = 0; j < 4; ++j) {
    int idx = idx0 + j;
    if (idx < n) {
      rowptr[idx] = run;
      run += v[j];
      if (idx == n - 1) rowptr[n] = run;
    }
  }
}

// init bin cursors
__global__ void init_bins_kernel(int* __restrict__ gcur) {
  const int t = threadIdx.x;
  if (t < MAXBINS) gcur[t * 16] = t * BIN_SZ;  // padded: one counter per 64B line
}

// ---------------------------------------------------------------------------
// Pass A v3: block-level two-phase binning. One gcur atomic per bin per BLOCK
// (chain length = grid size, not batch count).
// Phase 1: decode + cursor atomic; write (pos,nbr) unsorted & coalesced to
//          scratch; accumulate per-block bin histogram in LDS.
// Reserve: one atomicAdd(gcur[bin]) per non-empty bin.
// Phase 2: re-read own scratch (L2-hot, coalesced); dst = gb[bin]+ofs[bin]++
//          (LDS atomic); write record to gbuf (bin-grouped -> L2 line merge).
// ---------------------------------------------------------------------------
__global__ __launch_bounds__(256) void build_passA_kernel(
    const int* __restrict__ pbs, const int* __restrict__ pbd,
    const int* __restrict__ pcs, const int* __restrict__ pcd,
    const int* __restrict__ pss, const int* __restrict__ psd,
    const int* __restrict__ ups, const int* __restrict__ upd,
    int nPB, int nPC, int nPS, int nD, int* __restrict__ cursor,
    uint2* __restrict__ scratch, uint2* __restrict__ gbuf, int* __restrict__ gcur) {
  __shared__ int lcnt[MAXBINS];
  __shared__ int gb[MAXBINS];
  __shared__ int ofs[MAXBINS];
  const int t = threadIdx.x;
  const int per = (nD + gridDim.x - 1) / gridDim.x;
  const int start = blockIdx.x * per;
  const int end = (start + per < nD) ? (start + per) : nD;

  if (t < MAXBINS) {
    lcnt[t] = 0;
    ofs[t] = 0;
  }
  __syncthreads();

  // phase 1: decode, reserve CSR slot, stash unsorted, histogram bins
  for (int i = start + t; i < end; i += 256) {
    int a, b;
    decode_edge(i, pbs, pbd, pcs, pcd, pss, psd, ups, upd, nPB, nPC, nPS, a, b);
    const int p = atomicAdd(&cursor[a], 1);  // cursor pre-init = rowptr
    scratch[i] = make_uint2((u32)p, (u32)b);
    atomicAdd(&lcnt[p >> 16], 1);  // p / BIN_SZ
  }
  __syncthreads();

  // reserve global room: one atomic per bin per block
  if (t < MAXBINS) {
    const int v = lcnt[t];
    if (v > 0) gb[t] = atomicAdd(&gcur[t * 16], v);
  }
  __syncthreads();

  // phase 2: regroup by bin into gbuf
  for (int i = start + t; i < end; i += 256) {
    const uint2 r = scratch[i];  // same thread wrote it; self-visible
    const int bb = r.x >> 16;
    const int d = atomicAdd(&ofs[bb], 1);
    gbuf[gb[bb] + d] = r;
  }
}

// Pass B: one WG per bin; stream the records passA deposited (end = gcur),
// scatter into this bin's 256KB eidx window (L2-resident -> merged lines).
__global__ __launch_bounds__(512) void build_passB_kernel(
    const uint2* __restrict__ gbuf, const int* __restrict__ gcur,
    int* __restrict__ eidx) {
  const int b = blockIdx.x;
  const int start = b * BIN_SZ;
  const int end = gcur[b * 16];  // final fill level of this bin
  for (int i = start + threadIdx.x; i < end; i += 512) {
    const uint2 r = gbuf[i];
    eidx[r.x] = (int)r.y;
  }
}

// ---------------------------------------------------------------------------
// Gather-mean: sout[node][:] = bf16(mean_{j in N(node)} xin[j][:]).
// ---------------------------------------------------------------------------
__global__ __launch_bounds__(256) void gather_mean_kernel(
    const int* __restrict__ rowptr, const int* __restrict__ eidx,
    const u32* __restrict__ xin, u32* __restrict__ sout) {
  const int lane = threadIdx.x & 63;
  const int q = lane & 31;
  const int h = lane >> 5;
  const int wid0 = blockIdx.x * 4 + (threadIdx.x >> 6);
  const int nW = gridDim.x * 4;
  for (int node = wid0; node < NN; node += nW) {
    const int r0 = rowptr[node], r1 = rowptr[node + 1];
    float sl = 0.f, sh = 0.f;
    for (int e = r0; e < r1; e += 8) {
      int nj[4];
#pragma unroll
      for (int j = 0; j < 4; ++j) {
        const int ee = e + 2 * j + h;
        const int ec = (ee < r1 - 1) ? ee : (r1 - 1);
        nj[j] = eidx[ec];
      }
      u32 rv[4];
#pragma unroll
      for (int j = 0; j < 4; ++j) {
        u32 r = xin[(size_t)nj[j] * 32 + q];
        rv[j] = (e + 2 * j + h < r1) ? r : 0u;
      }
#pragma unroll
      for (int j = 0; j < 4; ++j) {
        sl += uasf(rv[j] << 16);
        sh += uasf(rv[j] & 0xffff0000u);
      }
    }
    sl += __shfl_xor(sl, 32);
    sh += __shfl_xor(sh, 32);
    if (h == 0) {
      const int deg = r1 - r0;
      const float inv = (deg > 0) ? (1.f / (float)deg) : 1.f;
      const u32 o = (u32)f2bf(sl * inv) | ((u32)f2bf(sh * inv) << 16);
      sout[(size_t)node * 32 + q] = o;
    }
  }
}

// ---------------------------------------------------------------------------
// Dense layer GEMM: out = act(S @ Wl + bl + X @ Wr), S,X bf16 [NN][64].
// ---------------------------------------------------------------------------
template <int DOUT, bool RELU>
__global__ __launch_bounds__(256) void layer_gemm_kernel(
    const u32* __restrict__ S, const u32* __restrict__ X,
    const float* __restrict__ Wl, const float* __restrict__ bl,
    const float* __restrict__ Wr, void* __restrict__ outv) {
  constexpr int NC = DOUT / 4;
  constexpr int NR = 256 / NC;
  constexpr int R = 128 / NR;
  __shared__ __align__(16) u32 lS[128 * 32];
  __shared__ __align__(16) u32 lX[128 * 32];
  __shared__ __align__(16) float lWl[64 * DOUT];
  __shared__ __align__(16) float lWr[64 * DOUT];
  const int t = threadIdx.x;
  const int row0 = blockIdx.x * 128;

#pragma unroll
  for (int i = 0; i < (64 * DOUT) / 1024; ++i) {
    const int idx = i * 256 + t;
    reinterpret_cast<float4*>(lWl)[idx] = reinterpret_cast<const float4*>(Wl)[idx];
    reinterpret_cast<float4*>(lWr)[idx] = reinterpret_cast<const float4*>(Wr)[idx];
  }
#pragma unroll
  for (int i = 0; i < 4; ++i) {
    const int idx = i * 256 + t;
    const int r = idx >> 3, c = idx & 7;
    uint4 vs = make_uint4(0u, 0u, 0u, 0u), vx = vs;
    if (row0 + r < NN) {
      vs = reinterpret_cast<const uint4*>(S)[(size_t)(row0 + r) * 8 + c];
      vx = reinterpret_cast<const uint4*>(X)[(size_t)(row0 + r) * 8 + c];
    }
    reinterpret_cast<uint4*>(lS)[idx] = vs;
    reinterpret_cast<uint4*>(lX)[idx] = vx;
  }
  __syncthreads();

  const int cg = t % NC, rg = t / NC;
  const int c0 = cg * 4;
  float acc[R][4];
#pragma unroll
  for (int r = 0; r < R; ++r)
#pragma unroll
    for (int c = 0; c < 4; ++c) acc[r][c] = 0.f;

  for (int kq = 0; kq < 16; ++kq) {
    float4 wl4[4], wr4[4];
#pragma unroll
    for (int j = 0; j < 4; ++j) {
      wl4[j] = *reinterpret_cast<const float4*>(&lWl[(kq * 4 + j) * DOUT + c0]);
      wr4[j] = *reinterpret_cast<const float4*>(&lWr[(kq * 4 + j) * DOUT + c0]);
    }
#pragma unroll
    for (int r = 0; r < R; ++r) {
      const int row = rg * R + r;
      const uint2 sv = *reinterpret_cast<const uint2*>(&lS[row * 32 + kq * 2]);
      const uint2 xv = *reinterpret_cast<const uint2*>(&lX[row * 32 + kq * 2]);
      const float sf[4] = {uasf(sv.x << 16), uasf(sv.x & 0xffff0000u),
                           uasf(sv.y << 16), uasf(sv.y & 0xffff0000u)};
      const float xf[4] = {uasf(xv.x << 16), uasf(xv.x & 0xffff0000u),
                           uasf(xv.y << 16), uasf(xv.y & 0xffff0000u)};
#pragma unroll
      for (int j = 0; j < 4; ++j) {
        acc[r][0] = fmaf(sf[j], wl4[j].x, acc[r][0]);
        acc[r][1] = fmaf(sf[j], wl4[j].y, acc[r][1]);
        acc[r][2] = fmaf(sf[j], wl4[j].z, acc[r][2]);
        acc[r][3] = fmaf(sf[j], wl4[j].w, acc[r][3]);
        acc[r][0] = fmaf(xf[j], wr4[j].x, acc[r][0]);
        acc[r][1] = fmaf(xf[j], wr4[j].y, acc[r][1]);
        acc[r][2] = fmaf(xf[j], wr4[j].z, acc[r][2]);
        acc[r][3] = fmaf(xf[j], wr4[j].w, acc[r][3]);
      }
    }
  }

  const float b0 = bl[c0 + 0], b1 = bl[c0 + 1], b2 = bl[c0 + 2], b3 = bl[c0 + 3];
#pragma unroll
  for (int r = 0; r < R; ++r) {
    const int grow = row0 + rg * R + r;
    if (grow < NN) {
      float o0 = acc[r][0] + b0, o1 = acc[r][1] + b1, o2 = acc[r][2] + b2, o3 = acc[r][3] + b3;
      if (RELU) {
        o0 = fmaxf(o0, 0.f); o1 = fmaxf(o1, 0.f); o2 = fmaxf(o2, 0.f); o3 = fmaxf(o3, 0.f);
      }
      if (DOUT == 64) {
        ushort4 o;
        o.x = f2bf(o0); o.y = f2bf(o1); o.z = f2bf(o2); o.w = f2bf(o3);
        *reinterpret_cast<ushort4*>((u16*)outv + (size_t)grow * 64 + c0) = o;
      } else {
        float4 o = make_float4(o0, o1, o2, o3);
        *reinterpret_cast<float4*>((float*)outv + (size_t)grow * 32 + c0) = o;
      }
    }
  }
}

// ---------------------------------------------------------------------------
extern "C" void kernel_launch(void* const* d_in, const int* in_sizes, int n_in,
                              void* d_out, int out_size, void* d_ws, size_t ws_size,
                              hipStream_t stream) {
  const float* product_x = (const float*)d_in[0];
  const float* user_emb = (const float*)d_in[1];
  const float* brand_emb = (const float*)d_in[2];
  const float* cat_emb = (const float*)d_in[3];
  const float* shop_emb = (const float*)d_in[4];
  const float* proj_W = (const float*)d_in[5];
  const float* proj_b = (const float*)d_in[6];
  const float* c1_Wl = (const float*)d_in[7];
  const float* c1_bl = (const float*)d_in[8];
  const float* c1_Wr = (const float*)d_in[9];
  const float* c2_Wl = (const float*)d_in[10];
  const float* c2_bl = (const float*)d_in[11];
  const float* c2_Wr = (const float*)d_in[12];
  const int* pb_src = (const int*)d_in[13];
  const int* pb_dst = (const int*)d_in[14];
  const int* pc_src = (const int*)d_in[15];
  const int* pc_dst = (const int*)d_in[16];
  const int* ps_src = (const int*)d_in[17];
  const int* ps_dst = (const int*)d_in[18];
  const int* up_src = (const int*)d_in[19];
  const int* up_dst = (const int*)d_in[20];
  const int nPB = in_sizes[13], nPC = in_sizes[15], nPS = in_sizes[17], nUP = in_sizes[19];
  const int nE = nPB + nPC + nPS + nUP;
  const int nD = 2 * nE;
  const int nbins = (nD + BIN_SZ - 1) / BIN_SZ;  // 55 for default sizes

  // workspace layout (bf16 tables as u16/u32 views)
  u16* xb = (u16*)d_ws;                          // [NN*64] bf16
  u16* out1 = xb + (size_t)NN * 64;              // [NN*64] bf16
  u16* sbuf = out1 + (size_t)NN * 64;            // [NN*64] bf16 (reused both layers)
  int* eidx = (int*)(sbuf + (size_t)NN * 64);    // [nD]
  int* rowptr = eidx + nD;                       // [NN+1]
  int* cnt = rowptr + (NN + 1);                  // [NN]
  int* cursor = cnt + NN;                        // [NN]
  int* blockSums = cursor + NN;                  // [512]
  int* gcur = blockSums + 512;                   // [MAXBINS*16] padded
  // aliased scratch (dead before their regions' first real write):
  uint2* gbuf = (uint2*)sbuf;      // [nD] 28.8MB <= 39.4MB; dead until gather1
  uint2* scratch = (uint2*)out1;   // [nD] 28.8MB <= 39.4MB; dead until gemm1

  hipMemsetAsync(cnt, 0, NN * sizeof(int), stream);

  degree_all_kernel<<<(nD + 255) / 256, 256, 0, stream>>>(
      pb_src, pb_dst, pc_src, pc_dst, ps_src, ps_dst, up_src, up_dst, nPB, nPC, nPS, nD, cnt);

  const int nb = (NN + 1023) / 1024;  // 301
  scan1_kernel<<<nb, 256, 0, stream>>>(cnt, blockSums, NN);
  scan2_kernel<<<1, 512, 0, stream>>>(blockSums, nb);
  scan3_kernel<<<nb, 256, 0, stream>>>(cnt, blockSums, rowptr, NN);

  // cursor <- rowptr (running write positions), then pos = cursor[a]++.
  hipMemcpyAsync(cursor, rowptr, NN * sizeof(int), hipMemcpyDeviceToDevice, stream);

  init_bins_kernel<<<1, 128, 0, stream>>>(gcur);
  build_passA_kernel<<<512, 256, 0, stream>>>(
      pb_src, pb_dst, pc_src, pc_dst, ps_src, ps_dst, up_src, up_dst, nPB, nPC, nPS, nD,
      cursor, scratch, gbuf, gcur);
  build_passB_kernel<<<nbins, 512, 0, stream>>>(gbuf, gcur, eidx);

  proj_mfma_kernel<<<(NP + 127) / 128, 256, 0, stream>>>(product_x, proj_W, proj_b, xb);
  cvt_emb_kernel<<<((NU + NBR + NCAT + NSH) * 16 + 255) / 256, 256, 0, stream>>>(
      user_emb, brand_emb, cat_emb, shop_emb, xb);

  // Layer 1
  gather_mean_kernel<<<4096, 256, 0, stream>>>(rowptr, eidx, (const u32*)xb, (u32*)sbuf);
  layer_gemm_kernel<64, true><<<(NN + 127) / 128, 256, 0, stream>>>(
      (const u32*)sbuf, (const u32*)xb, c1_Wl, c1_bl, c1_Wr, out1);
  // Layer 2
  gather_mean_kernel<<<4096, 256, 0, stream>>>(rowptr, eidx, (const u32*)out1, (u32*)sbuf);
  layer_gemm_kernel<32, false><<<(NN + 127) / 128, 256, 0, stream>>>(
      (const u32*)sbuf, (const u32*)out1, c2_Wl, c2_bl, c2_Wr, d_out);
}

// Round 9
// 621.426 us; speedup vs baseline: 1.8513x; 1.5851x over previous
//
#include <hip/hip_runtime.h>

#define NP 200000
#define NU 100000
#define NBR 5000
#define NCAT 2000
#define NSH 1000
#define NN (NP + NU + NBR + NCAT + NSH) /* 308000 */
#define OFF_U NP
#define OFF_B (NP + NU)
#define OFF_C (NP + NU + NBR)
#define OFF_S (NP + NU + NBR + NCAT)

#define NBINS 67 /* class-aware node bins: 25 P(8192) + 13 U(8192) + 5 B(1024) + 8 C(256) + 16 S(64) */

typedef unsigned short u16;
typedef unsigned int u32;
typedef __attribute__((ext_vector_type(8))) short short8;
typedef __attribute__((ext_vector_type(4))) float f32x4;

__device__ __forceinline__ u16 f2bf(float f) {
  union { float f; unsigned u; } v;
  v.f = f;
  unsigned r = (v.u + 0x7fffu + ((v.u >> 16) & 1u)) >> 16;  // RNE
  return (u16)r;
}
__device__ __forceinline__ float uasf(u32 u) {
  union { u32 u; float f; } v;
  v.u = u;
  return v.f;
}
// pack 2 fp32 -> 2 bf16 (RNE) in one instr
__device__ __forceinline__ u32 cvtpk(float lo, float hi) {
  u32 r;
  asm("v_cvt_pk_bf16_f32 %0, %1, %2" : "=v"(r) : "v"(lo), "v"(hi));
  return r;
}

// node -> bin (class-aware ranges; each bin spans <= 8192 nodes)
__device__ __forceinline__ int bin_of(int a) {
  if (a < OFF_U) return a >> 13;
  if (a < OFF_B) return 25 + ((a - OFF_U) >> 13);
  if (a < OFF_C) return 38 + ((a - OFF_B) >> 10);
  if (a < OFF_S) return 43 + ((a - OFF_C) >> 8);
  return 51 + ((a - OFF_S) >> 6);
}
__device__ __forceinline__ void bin_range(int bin, int& n0, int& n1) {
  if (bin < 25) {
    n0 = bin << 13; n1 = min(n0 + 8192, OFF_U);
  } else if (bin < 38) {
    n0 = OFF_U + ((bin - 25) << 13); n1 = min(n0 + 8192, OFF_B);
  } else if (bin < 43) {
    n0 = OFF_B + ((bin - 38) << 10); n1 = min(n0 + 1024, OFF_C);
  } else if (bin < 51) {
    n0 = OFF_C + ((bin - 43) << 8); n1 = min(n0 + 256, OFF_S);
  } else {
    n0 = OFF_S + ((bin - 51) << 6); n1 = min(n0 + 64, NN);
  }
}

// ---------------------------------------------------------------------------
// MFMA projection: xb[r][c] = bf16(relu(px[r][:] @ W[:][c] + b[c])), r<NP.
// ---------------------------------------------------------------------------
__global__ __launch_bounds__(256) void proj_mfma_kernel(
    const float* __restrict__ px, const float* __restrict__ W,
    const float* __restrict__ bias, u16* __restrict__ xb) {
  __shared__ u16 lA[2][128 * 32];  // 8 KB per buffer, bf16, swizzled
  const int t = threadIdx.x;
  const int l = t & 63;
  const int wid = t >> 6;
  const int row0 = blockIdx.x * 128;

  const int n0 = wid * 16 + (l & 15);
  const int kb = (l >> 4) * 8;
  short8 bf[12];
#pragma unroll
  for (int kt = 0; kt < 12; ++kt) {
    union { u32 p[4]; short8 s; } uu;
#pragma unroll
    for (int j = 0; j < 4; ++j) {
      const float lo = W[(size_t)(kt * 32 + kb + 2 * j) * 64 + n0];
      const float hi = W[(size_t)(kt * 32 + kb + 2 * j + 1) * 64 + n0];
      uu.p[j] = cvtpk(lo, hi);
    }
    bf[kt] = uu.s;
  }
  const float bv = bias[n0];

  f32x4 acc[8];
#pragma unroll
  for (int rt = 0; rt < 8; ++rt) {
    f32x4 z = {0.f, 0.f, 0.f, 0.f};
    acc[rt] = z;
  }

  const int fr_base = (((l & 15) * 64 + (l >> 4) * 16)) ^ ((l & 7) << 4);

  float4 sreg[4];
#pragma unroll
  for (int i = 0; i < 4; ++i) {
    const int qi = t + 256 * i;
    const int r = qi >> 3, q = qi & 7;
    const int grow = row0 + r;
    sreg[i] = (grow < NP) ? *reinterpret_cast<const float4*>(px + (size_t)grow * 384 + q * 4)
                          : make_float4(0.f, 0.f, 0.f, 0.f);
  }
#pragma unroll
  for (int i = 0; i < 4; ++i) {
    const int qi = t + 256 * i;
    const int r = qi >> 3, q = qi & 7;
    const int a16 = (((r * 64 + q * 8)) ^ ((r & 7) << 4)) >> 1;
    const u32 p0 = cvtpk(sreg[i].x, sreg[i].y);
    const u32 p1 = cvtpk(sreg[i].z, sreg[i].w);
    *reinterpret_cast<uint2*>(&lA[0][a16]) = make_uint2(p0, p1);
  }

#pragma unroll
  for (int kt = 0; kt < 12; ++kt) {
    const int cur = kt & 1;
    if (kt + 1 < 12) {
#pragma unroll
      for (int i = 0; i < 4; ++i) {
        const int qi = t + 256 * i;
        const int r = qi >> 3, q = qi & 7;
        const int grow = row0 + r;
        sreg[i] = (grow < NP)
                      ? *reinterpret_cast<const float4*>(px + (size_t)grow * 384 +
                                                         (kt + 1) * 32 + q * 4)
                      : make_float4(0.f, 0.f, 0.f, 0.f);
      }
    }
    __syncthreads();
#pragma unroll
    for (int rt = 0; rt < 8; ++rt) {
      const short8 af =
          *reinterpret_cast<const short8*>(&lA[cur][(fr_base + rt * 1024) >> 1]);
      acc[rt] = __builtin_amdgcn_mfma_f32_16x16x32_bf16(af, bf[kt], acc[rt], 0, 0, 0);
    }
    if (kt + 1 < 12) {
#pragma unroll
      for (int i = 0; i < 4; ++i) {
        const int qi = t + 256 * i;
        const int r = qi >> 3, q = qi & 7;
        const int a16 = (((r * 64 + q * 8)) ^ ((r & 7) << 4)) >> 1;
        const u32 p0 = cvtpk(sreg[i].x, sreg[i].y);
        const u32 p1 = cvtpk(sreg[i].z, sreg[i].w);
        *reinterpret_cast<uint2*>(&lA[cur ^ 1][a16]) = make_uint2(p0, p1);
      }
    }
  }

#pragma unroll
  for (int rt = 0; rt < 8; ++rt) {
#pragma unroll
    for (int r = 0; r < 4; ++r) {
      const int grow = row0 + rt * 16 + (l >> 4) * 4 + r;
      if (grow < NP)
        xb[(size_t)grow * 64 + n0] = f2bf(fmaxf(acc[rt][r] + bv, 0.f));
    }
  }
}

// ---------------------------------------------------------------------------
// Fused fp32->bf16 conversion of all 4 embedding tables into xb.
// ---------------------------------------------------------------------------
__global__ void cvt_emb_kernel(const float* __restrict__ ue, const float* __restrict__ be,
                               const float* __restrict__ ce, const float* __restrict__ se,
                               u16* __restrict__ xb) {
  const int i = blockIdx.x * 256 + threadIdx.x;
  const int totalQ = (NU + NBR + NCAT + NSH) * 16;
  if (i >= totalQ) return;
  const int row = i >> 4, q = i & 15;
  const float* src;
  int lrow;
  if (row < NU) {
    src = ue; lrow = row;
  } else if (row < NU + NBR) {
    src = be; lrow = row - NU;
  } else if (row < NU + NBR + NCAT) {
    src = ce; lrow = row - NU - NBR;
  } else {
    src = se; lrow = row - NU - NBR - NCAT;
  }
  const float4 v = reinterpret_cast<const float4*>(src)[(size_t)lrow * 16 + q];
  ushort4 o;
  o.x = f2bf(v.x);
  o.y = f2bf(v.y);
  o.z = f2bf(v.z);
  o.w = f2bf(v.w);
  reinterpret_cast<ushort4*>(xb + (size_t)(OFF_U + row) * 64)[q] = o;
}

// ---------------------------------------------------------------------------
// Directed-entry decode. i in [0, 2*nE).
// ---------------------------------------------------------------------------
__device__ __forceinline__ void decode_edge(
    int i, const int* pbs, const int* pbd, const int* pcs, const int* pcd,
    const int* pss, const int* psd, const int* ups, const int* upd,
    int nPB, int nPC, int nPS, int& a, int& b) {
  const int d = i & 1;
  int eu = i >> 1;
  int a0, b0;
  if (eu < nPB) {
    a0 = pbs[eu]; b0 = pbd[eu] + OFF_B;
  } else {
    eu -= nPB;
    if (eu < nPC) {
      a0 = pcs[eu]; b0 = pcd[eu] + OFF_C;
    } else {
      eu -= nPC;
      if (eu < nPS) {
        a0 = pss[eu]; b0 = psd[eu] + OFF_S;
      } else {
        eu -= nPS;
        a0 = ups[eu] + OFF_U; b0 = upd[eu];
      }
    }
  }
  a = d ? b0 : a0;
  b = d ? a0 : b0;
}

#define EDGE_ARGS const int* __restrict__ pbs, const int* __restrict__ pbd, \
                  const int* __restrict__ pcs, const int* __restrict__ pcd, \
                  const int* __restrict__ pss, const int* __restrict__ psd, \
                  const int* __restrict__ ups, const int* __restrict__ upd, \
                  int nPB, int nPC, int nPS, int nD
#define EDGE_PASS pbs, pbd, pcs, pcd, pss, psd, ups, upd, nPB, nPC, nPS

// ---------------------------------------------------------------------------
// 1. Global histogram of directed entries per node-bin (34k global atomics).
// ---------------------------------------------------------------------------
__global__ __launch_bounds__(256) void bin_count_kernel(EDGE_ARGS,
                                                        int* __restrict__ binCnt) {
  __shared__ int lh[NBINS];
  const int t = threadIdx.x;
  if (t < NBINS) lh[t] = 0;
  __syncthreads();
  for (int i = blockIdx.x * 256 + t; i < nD; i += gridDim.x * 256) {
    int a, b;
    decode_edge(i, EDGE_PASS, a, b);
    (void)b;
    atomicAdd(&lh[bin_of(a)], 1);
  }
  __syncthreads();
  if (t < NBINS && lh[t] > 0) atomicAdd(&binCnt[t], lh[t]);
}

// 2. Tiny scan: binCnt[NBINS] -> binBase[NBINS+1]; init gcur.
__global__ void bin_scan_kernel(const int* __restrict__ binCnt, int* __restrict__ binBase,
                                int* __restrict__ gcur) {
  __shared__ int base[NBINS + 1];
  if (threadIdx.x == 0) {
    int run = 0;
    for (int b = 0; b < NBINS; ++b) {
      base[b] = run;
      run += binCnt[b];
    }
    base[NBINS] = run;
  }
  __syncthreads();
  if (threadIdx.x <= NBINS) binBase[threadIdx.x] = base[threadIdx.x];
  if (threadIdx.x < NBINS) gcur[threadIdx.x * 16] = base[threadIdx.x];
}

// ---------------------------------------------------------------------------
// 3. Two-phase block binning by node-bin: LDS hist -> one gcur reserve per
//    bin per block -> re-decode (L2-hot) -> grouped coalesced record writes.
// ---------------------------------------------------------------------------
__global__ __launch_bounds__(256) void bin_scatter_kernel(EDGE_ARGS,
                                                          uint2* __restrict__ gbuf,
                                                          int* __restrict__ gcur) {
  __shared__ int lh[NBINS];
  __shared__ int gb[NBINS];
  __shared__ int ofs[NBINS];
  const int t = threadIdx.x;
  const int per = (nD + gridDim.x - 1) / gridDim.x;
  const int start = blockIdx.x * per;
  const int end = (start + per < nD) ? (start + per) : nD;

  if (t < NBINS) {
    lh[t] = 0;
    ofs[t] = 0;
  }
  __syncthreads();
  for (int i = start + t; i < end; i += 256) {
    int a, b;
    decode_edge(i, EDGE_PASS, a, b);
    (void)b;
    atomicAdd(&lh[bin_of(a)], 1);
  }
  __syncthreads();
  if (t < NBINS && lh[t] > 0) gb[t] = atomicAdd(&gcur[t * 16], lh[t]);
  __syncthreads();
  for (int i = start + t; i < end; i += 256) {
    int a, b;
    decode_edge(i, EDGE_PASS, a, b);
    const int bb = bin_of(a);
    const int d = atomicAdd(&ofs[bb], 1);
    gbuf[gb[bb] + d] = make_uint2((u32)a, (u32)b);
  }
}

// ---------------------------------------------------------------------------
// 4. Per-bin-slice node counting: LDS counters, coalesced partial writes.
//    grid = NBINS*4; block (bin, s) owns records slice s/4 of bin.
// ---------------------------------------------------------------------------
__global__ __launch_bounds__(256) void count_nodes_kernel(
    const uint2* __restrict__ gbuf, const int* __restrict__ binBase,
    int* __restrict__ cntp) {
  __shared__ int cnt[8192];
  const int bin = blockIdx.x >> 2, s = blockIdx.x & 3;
  int n0, n1;
  bin_range(bin, n0, n1);
  const int rb = binBase[bin], re = binBase[bin + 1];
  const int len = re - rb;
  const int s0 = rb + (len * s) / 4;
  const int s1 = rb + (len * (s + 1)) / 4;
  for (int i = threadIdx.x; i < 8192; i += 256) cnt[i] = 0;
  __syncthreads();
  for (int r = s0 + threadIdx.x; r < s1; r += 256)
    atomicAdd(&cnt[(int)gbuf[r].x - n0], 1);
  __syncthreads();
  for (int n = n0 + threadIdx.x; n < n1; n += 256)
    cntp[s * NN + n] = cnt[n - n0];
}

// 3-kernel exclusive scan over sum of 4 partials -> rowptr[NN+1]
__global__ __launch_bounds__(256) void scan1_kernel(const int* __restrict__ cntp,
                                                    int* __restrict__ blockSums, int n) {
  __shared__ int sdata[256];
  const int base = blockIdx.x * 1024;
  int s = 0;
  for (int i = threadIdx.x; i < 1024; i += 256) {
    int idx = base + i;
    if (idx < n)
      s += cntp[idx] + cntp[NN + idx] + cntp[2 * NN + idx] + cntp[3 * NN + idx];
  }
  sdata[threadIdx.x] = s;
  __syncthreads();
  for (int off = 128; off > 0; off >>= 1) {
    if (threadIdx.x < off) sdata[threadIdx.x] += sdata[threadIdx.x + off];
    __syncthreads();
  }
  if (threadIdx.x == 0) blockSums[blockIdx.x] = sdata[0];
}

__global__ __launch_bounds__(512) void scan2_kernel(int* __restrict__ blockSums, int nb) {
  __shared__ int sd[512];
  const int t = threadIdx.x;
  const int v = (t < nb) ? blockSums[t] : 0;
  sd[t] = v;
  __syncthreads();
  for (int off = 1; off < 512; off <<= 1) {
    int add = (t >= off) ? sd[t - off] : 0;
    __syncthreads();
    sd[t] += add;
    __syncthreads();
  }
  if (t < nb) blockSums[t] = sd[t] - v;  // exclusive
}

__global__ __launch_bounds__(256) void scan3_kernel(const int* __restrict__ cntp,
                                                    const int* __restrict__ blockSums,
                                                    int* __restrict__ rowptr, int n) {
  __shared__ int wsum[4];
  const int base = blockIdx.x * 1024;
  const int t = threadIdx.x, lane = t & 63, wid = t >> 6;
  const int idx0 = base + t * 4;
  int v[4];
#pragma unroll
  for (int j = 0; j < 4; ++j) {
    int idx = idx0 + j;
    v[j] = (idx < n)
               ? cntp[idx] + cntp[NN + idx] + cntp[2 * NN + idx] + cntp[3 * NN + idx]
               : 0;
  }
  const int s = v[0] + v[1] + v[2] + v[3];
  int incl = s;
  for (int off = 1; off < 64; off <<= 1) {
    int tt = __shfl_up(incl, off);
    if (lane >= off) incl += tt;
  }
  if (lane == 63) wsum[wid] = incl;
  __syncthreads();
  int wOff = 0;
#pragma unroll
  for (int w = 0; w < 4; ++w)
    if (w < wid) wOff += wsum[w];
  int run = blockSums[blockIdx.x] + wOff + (incl - s);
#pragma unroll
  for (int j = 0; j < 4; ++j) {
    int idx = idx0 + j;
    if (idx < n) {
      rowptr[idx] = run;
      run += v[j];
      if (idx == n - 1) rowptr[n] = run;
    }
  }
}

// ---------------------------------------------------------------------------
// 6. Final fill: LDS cursor (rowptr + prefix of earlier slices), LDS-atomic
//    position assignment, scatter confined to bin's eidx window (L2-merged).
// ---------------------------------------------------------------------------
__global__ __launch_bounds__(256) void fill_scatter_kernel(
    const uint2* __restrict__ gbuf, const int* __restrict__ binBase,
    const int* __restrict__ rowptr, const int* __restrict__ cntp,
    int* __restrict__ eidx) {
  __shared__ int cur[8192];
  const int bin = blockIdx.x >> 2, s = blockIdx.x & 3;
  int n0, n1;
  bin_range(bin, n0, n1);
  const int rb = binBase[bin], re = binBase[bin + 1];
  const int len = re - rb;
  const int s0 = rb + (len * s) / 4;
  const int s1 = rb + (len * (s + 1)) / 4;
  for (int n = n0 + threadIdx.x; n < n1; n += 256) {
    int c = rowptr[n];
    if (s > 0) c += cntp[n];
    if (s > 1) c += cntp[NN + n];
    if (s > 2) c += cntp[2 * NN + n];
    cur[n - n0] = c;
  }
  __syncthreads();
  for (int r = s0 + threadIdx.x; r < s1; r += 256) {
    const uint2 rec = gbuf[r];
    const int p = atomicAdd(&cur[(int)rec.x - n0], 1);
    eidx[p] = (int)rec.y;
  }
}

// ---------------------------------------------------------------------------
// Gather-mean: sout[node][:] = bf16(mean_{j in N(node)} xin[j][:]).
// ---------------------------------------------------------------------------
__global__ __launch_bounds__(256) void gather_mean_kernel(
    const int* __restrict__ rowptr, const int* __restrict__ eidx,
    const u32* __restrict__ xin, u32* __restrict__ sout) {
  const int lane = threadIdx.x & 63;
  const int q = lane & 31;
  const int h = lane >> 5;
  const int wid0 = blockIdx.x * 4 + (threadIdx.x >> 6);
  const int nW = gridDim.x * 4;
  for (int node = wid0; node < NN; node += nW) {
    const int r0 = rowptr[node], r1 = rowptr[node + 1];
    float sl = 0.f, sh = 0.f;
    for (int e = r0; e < r1; e += 8) {
      int nj[4];
#pragma unroll
      for (int j = 0; j < 4; ++j) {
        const int ee = e + 2 * j + h;
        const int ec = (ee < r1 - 1) ? ee : (r1 - 1);
        nj[j] = eidx[ec];
      }
      u32 rv[4];
#pragma unroll
      for (int j = 0; j < 4; ++j) {
        u32 r = xin[(size_t)nj[j] * 32 + q];
        rv[j] = (e + 2 * j + h < r1) ? r : 0u;
      }
#pragma unroll
      for (int j = 0; j < 4; ++j) {
        sl += uasf(rv[j] << 16);
        sh += uasf(rv[j] & 0xffff0000u);
      }
    }
    sl += __shfl_xor(sl, 32);
    sh += __shfl_xor(sh, 32);
    if (h == 0) {
      const int deg = r1 - r0;
      const float inv = (deg > 0) ? (1.f / (float)deg) : 1.f;
      const u32 o = (u32)f2bf(sl * inv) | ((u32)f2bf(sh * inv) << 16);
      sout[(size_t)node * 32 + q] = o;
    }
  }
}

// ---------------------------------------------------------------------------
// Dense layer GEMM: out = act(S @ Wl + bl + X @ Wr), S,X bf16 [NN][64].
// ---------------------------------------------------------------------------
template <int DOUT, bool RELU>
__global__ __launch_bounds__(256) void layer_gemm_kernel(
    const u32* __restrict__ S, const u32* __restrict__ X,
    const float* __restrict__ Wl, const float* __restrict__ bl,
    const float* __restrict__ Wr, void* __restrict__ outv) {
  constexpr int NC = DOUT / 4;
  constexpr int NR = 256 / NC;
  constexpr int R = 128 / NR;
  __shared__ __align__(16) u32 lS[128 * 32];
  __shared__ __align__(16) u32 lX[128 * 32];
  __shared__ __align__(16) float lWl[64 * DOUT];
  __shared__ __align__(16) float lWr[64 * DOUT];
  const int t = threadIdx.x;
  const int row0 = blockIdx.x * 128;

#pragma unroll
  for (int i = 0; i < (64 * DOUT) / 1024; ++i) {
    const int idx = i * 256 + t;
    reinterpret_cast<float4*>(lWl)[idx] = reinterpret_cast<const float4*>(Wl)[idx];
    reinterpret_cast<float4*>(lWr)[idx] = reinterpret_cast<const float4*>(Wr)[idx];
  }
#pragma unroll
  for (int i = 0; i < 4; ++i) {
    const int idx = i * 256 + t;
    const int r = idx >> 3, c = idx & 7;
    uint4 vs = make_uint4(0u, 0u, 0u, 0u), vx = vs;
    if (row0 + r < NN) {
      vs = reinterpret_cast<const uint4*>(S)[(size_t)(row0 + r) * 8 + c];
      vx = reinterpret_cast<const uint4*>(X)[(size_t)(row0 + r) * 8 + c];
    }
    reinterpret_cast<uint4*>(lS)[idx] = vs;
    reinterpret_cast<uint4*>(lX)[idx] = vx;
  }
  __syncthreads();

  const int cg = t % NC, rg = t / NC;
  const int c0 = cg * 4;
  float acc[R][4];
#pragma unroll
  for (int r = 0; r < R; ++r)
#pragma unroll
    for (int c = 0; c < 4; ++c) acc[r][c] = 0.f;

  for (int kq = 0; kq < 16; ++kq) {
    float4 wl4[4], wr4[4];
#pragma unroll
    for (int j = 0; j < 4; ++j) {
      wl4[j] = *reinterpret_cast<const float4*>(&lWl[(kq * 4 + j) * DOUT + c0]);
      wr4[j] = *reinterpret_cast<const float4*>(&lWr[(kq * 4 + j) * DOUT + c0]);
    }
#pragma unroll
    for (int r = 0; r < R; ++r) {
      const int row = rg * R + r;
      const uint2 sv = *reinterpret_cast<const uint2*>(&lS[row * 32 + kq * 2]);
      const uint2 xv = *reinterpret_cast<const uint2*>(&lX[row * 32 + kq * 2]);
      const float sf[4] = {uasf(sv.x << 16), uasf(sv.x & 0xffff0000u),
                           uasf(sv.y << 16), uasf(sv.y & 0xffff0000u)};
      const float xf[4] = {uasf(xv.x << 16), uasf(xv.x & 0xffff0000u),
                           uasf(xv.y << 16), uasf(xv.y & 0xffff0000u)};
#pragma unroll
      for (int j = 0; j < 4; ++j) {
        acc[r][0] = fmaf(sf[j], wl4[j].x, acc[r][0]);
        acc[r][1] = fmaf(sf[j], wl4[j].y, acc[r][1]);
        acc[r][2] = fmaf(sf[j], wl4[j].z, acc[r][2]);
        acc[r][3] = fmaf(sf[j], wl4[j].w, acc[r][3]);
        acc[r][0] = fmaf(xf[j], wr4[j].x, acc[r][0]);
        acc[r][1] = fmaf(xf[j], wr4[j].y, acc[r][1]);
        acc[r][2] = fmaf(xf[j], wr4[j].z, acc[r][2]);
        acc[r][3] = fmaf(xf[j], wr4[j].w, acc[r][3]);
      }
    }
  }

  const float b0 = bl[c0 + 0], b1 = bl[c0 + 1], b2 = bl[c0 + 2], b3 = bl[c0 + 3];
#pragma unroll
  for (int r = 0; r < R; ++r) {
    const int grow = row0 + rg * R + r;
    if (grow < NN) {
      float o0 = acc[r][0] + b0, o1 = acc[r][1] + b1, o2 = acc[r][2] + b2, o3 = acc[r][3] + b3;
      if (RELU) {
        o0 = fmaxf(o0, 0.f); o1 = fmaxf(o1, 0.f); o2 = fmaxf(o2, 0.f); o3 = fmaxf(o3, 0.f);
      }
      if (DOUT == 64) {
        ushort4 o;
        o.x = f2bf(o0); o.y = f2bf(o1); o.z = f2bf(o2); o.w = f2bf(o3);
        *reinterpret_cast<ushort4*>((u16*)outv + (size_t)grow * 64 + c0) = o;
      } else {
        float4 o = make_float4(o0, o1, o2, o3);
        *reinterpret_cast<float4*>((float*)outv + (size_t)grow * 32 + c0) = o;
      }
    }
  }
}

// ---------------------------------------------------------------------------
extern "C" void kernel_launch(void* const* d_in, const int* in_sizes, int n_in,
                              void* d_out, int out_size, void* d_ws, size_t ws_size,
                              hipStream_t stream) {
  const float* product_x = (const float*)d_in[0];
  const float* user_emb = (const float*)d_in[1];
  const float* brand_emb = (const float*)d_in[2];
  const float* cat_emb = (const float*)d_in[3];
  const float* shop_emb = (const float*)d_in[4];
  const float* proj_W = (const float*)d_in[5];
  const float* proj_b = (const float*)d_in[6];
  const float* c1_Wl = (const float*)d_in[7];
  const float* c1_bl = (const float*)d_in[8];
  const float* c1_Wr = (const float*)d_in[9];
  const float* c2_Wl = (const float*)d_in[10];
  const float* c2_bl = (const float*)d_in[11];
  const float* c2_Wr = (const float*)d_in[12];
  const int* pb_src = (const int*)d_in[13];
  const int* pb_dst = (const int*)d_in[14];
  const int* pc_src = (const int*)d_in[15];
  const int* pc_dst = (const int*)d_in[16];
  const int* ps_src = (const int*)d_in[17];
  const int* ps_dst = (const int*)d_in[18];
  const int* up_src = (const int*)d_in[19];
  const int* up_dst = (const int*)d_in[20];
  const int nPB = in_sizes[13], nPC = in_sizes[15], nPS = in_sizes[17], nUP = in_sizes[19];
  const int nE = nPB + nPC + nPS + nUP;
  const int nD = 2 * nE;

  // workspace layout (bf16 tables as u16/u32 views)
  u16* xb = (u16*)d_ws;                          // [NN*64] bf16
  u16* out1 = xb + (size_t)NN * 64;              // [NN*64] bf16
  u16* sbuf = out1 + (size_t)NN * 64;            // [NN*64] bf16 (reused both layers)
  int* eidx = (int*)(sbuf + (size_t)NN * 64);    // [nD]
  int* rowptr = eidx + nD;                       // [NN+1]
  int* blockSums = rowptr + (NN + 1);            // [512]
  int* binCnt = blockSums + 512;                 // [128]
  int* binBase = binCnt + 128;                   // [NBINS+1]
  int* gcur = binBase + 128;                     // [NBINS*16] padded
  // aliased scratch (dead before their regions' first real write):
  uint2* gbuf = (uint2*)sbuf;  // [nD] 28.8MB <= 39.4MB; dead until gather1 writes sbuf
  int* cntp = (int*)out1;      // [4*NN] 4.9MB <= 39.4MB; dead until gemm1 writes out1

  hipMemsetAsync(binCnt, 0, 128 * sizeof(int), stream);

  bin_count_kernel<<<512, 256, 0, stream>>>(pb_src, pb_dst, pc_src, pc_dst, ps_src, ps_dst,
                                            up_src, up_dst, nPB, nPC, nPS, nD, binCnt);
  bin_scan_kernel<<<1, 128, 0, stream>>>(binCnt, binBase, gcur);
  bin_scatter_kernel<<<512, 256, 0, stream>>>(pb_src, pb_dst, pc_src, pc_dst, ps_src, ps_dst,
                                              up_src, up_dst, nPB, nPC, nPS, nD, gbuf, gcur);
  count_nodes_kernel<<<NBINS * 4, 256, 0, stream>>>(gbuf, binBase, cntp);

  const int nb = (NN + 1023) / 1024;  // 301
  scan1_kernel<<<nb, 256, 0, stream>>>(cntp, blockSums, NN);
  scan2_kernel<<<1, 512, 0, stream>>>(blockSums, nb);
  scan3_kernel<<<nb, 256, 0, stream>>>(cntp, blockSums, rowptr, NN);

  fill_scatter_kernel<<<NBINS * 4, 256, 0, stream>>>(gbuf, binBase, rowptr, cntp, eidx);

  proj_mfma_kernel<<<(NP + 127) / 128, 256, 0, stream>>>(product_x, proj_W, proj_b, xb);
  cvt_emb_kernel<<<((NU + NBR + NCAT + NSH) * 16 + 255) / 256, 256, 0, stream>>>(
      user_emb, brand_emb, cat_emb, shop_emb, xb);

  // Layer 1
  gather_mean_kernel<<<4096, 256, 0, stream>>>(rowptr, eidx, (const u32*)xb, (u32*)sbuf);
  layer_gemm_kernel<64, true><<<(NN + 127) / 128, 256, 0, stream>>>(
      (const u32*)sbuf, (const u32*)xb, c1_Wl, c1_bl, c1_Wr, out1);
  // Layer 2
  gather_mean_kernel<<<4096, 256, 0, stream>>>(rowptr, eidx, (const u32*)out1, (u32*)sbuf);
  layer_gemm_kernel<32, false><<<(NN + 127) / 128, 256, 0, stream>>>(
      (const u32*)sbuf, (const u32*)out1, c2_Wl, c2_bl, c2_Wr, d_out);
}

// Round 10
// 608.852 us; speedup vs baseline: 1.8895x; 1.0207x over previous
//
#include <hip/hip_runtime.h>

#define NP 200000
#define NU 100000
#define NBR 5000
#define NCAT 2000
#define NSH 1000
#define NN (NP + NU + NBR + NCAT + NSH) /* 308000 */
#define OFF_U NP
#define OFF_B (NP + NU)
#define OFF_C (NP + NU + NBR)
#define OFF_S (NP + NU + NBR + NCAT)

#define NBINS 67 /* class-aware node bins: 25 P(8192) + 13 U(8192) + 5 B(1024) + 8 C(256) + 16 S(64) */

typedef unsigned short u16;
typedef unsigned int u32;
typedef __attribute__((ext_vector_type(8))) short short8;
typedef __attribute__((ext_vector_type(4))) float f32x4;

__device__ __forceinline__ u16 f2bf(float f) {
  union { float f; unsigned u; } v;
  v.f = f;
  unsigned r = (v.u + 0x7fffu + ((v.u >> 16) & 1u)) >> 16;  // RNE
  return (u16)r;
}
__device__ __forceinline__ float uasf(u32 u) {
  union { u32 u; float f; } v;
  v.u = u;
  return v.f;
}
// pack 2 fp32 -> 2 bf16 (RNE) in one instr
__device__ __forceinline__ u32 cvtpk(float lo, float hi) {
  u32 r;
  asm("v_cvt_pk_bf16_f32 %0, %1, %2" : "=v"(r) : "v"(lo), "v"(hi));
  return r;
}

// node -> bin (class-aware ranges; each bin spans <= 8192 nodes)
__device__ __forceinline__ int bin_of(int a) {
  if (a < OFF_U) return a >> 13;
  if (a < OFF_B) return 25 + ((a - OFF_U) >> 13);
  if (a < OFF_C) return 38 + ((a - OFF_B) >> 10);
  if (a < OFF_S) return 43 + ((a - OFF_C) >> 8);
  return 51 + ((a - OFF_S) >> 6);
}
__device__ __forceinline__ void bin_range(int bin, int& n0, int& n1) {
  if (bin < 25) {
    n0 = bin << 13; n1 = min(n0 + 8192, OFF_U);
  } else if (bin < 38) {
    n0 = OFF_U + ((bin - 25) << 13); n1 = min(n0 + 8192, OFF_B);
  } else if (bin < 43) {
    n0 = OFF_B + ((bin - 38) << 10); n1 = min(n0 + 1024, OFF_C);
  } else if (bin < 51) {
    n0 = OFF_C + ((bin - 43) << 8); n1 = min(n0 + 256, OFF_S);
  } else {
    n0 = OFF_S + ((bin - 51) << 6); n1 = min(n0 + 64, NN);
  }
}

// ---------------------------------------------------------------------------
// MFMA projection: xb[r][c] = bf16(relu(px[r][:] @ W[:][c] + b[c])), r<NP.
// ---------------------------------------------------------------------------
__global__ __launch_bounds__(256) void proj_mfma_kernel(
    const float* __restrict__ px, const float* __restrict__ W,
    const float* __restrict__ bias, u16* __restrict__ xb) {
  __shared__ u16 lA[2][128 * 32];  // 8 KB per buffer, bf16, swizzled
  const int t = threadIdx.x;
  const int l = t & 63;
  const int wid = t >> 6;
  const int row0 = blockIdx.x * 128;

  const int n0 = wid * 16 + (l & 15);
  const int kb = (l >> 4) * 8;
  short8 bf[12];
#pragma unroll
  for (int kt = 0; kt < 12; ++kt) {
    union { u32 p[4]; short8 s; } uu;
#pragma unroll
    for (int j = 0; j < 4; ++j) {
      const float lo = W[(size_t)(kt * 32 + kb + 2 * j) * 64 + n0];
      const float hi = W[(size_t)(kt * 32 + kb + 2 * j + 1) * 64 + n0];
      uu.p[j] = cvtpk(lo, hi);
    }
    bf[kt] = uu.s;
  }
  const float bv = bias[n0];

  f32x4 acc[8];
#pragma unroll
  for (int rt = 0; rt < 8; ++rt) {
    f32x4 z = {0.f, 0.f, 0.f, 0.f};
    acc[rt] = z;
  }

  const int fr_base = (((l & 15) * 64 + (l >> 4) * 16)) ^ ((l & 7) << 4);

  float4 sreg[4];
#pragma unroll
  for (int i = 0; i < 4; ++i) {
    const int qi = t + 256 * i;
    const int r = qi >> 3, q = qi & 7;
    const int grow = row0 + r;
    sreg[i] = (grow < NP) ? *reinterpret_cast<const float4*>(px + (size_t)grow * 384 + q * 4)
                          : make_float4(0.f, 0.f, 0.f, 0.f);
  }
#pragma unroll
  for (int i = 0; i < 4; ++i) {
    const int qi = t + 256 * i;
    const int r = qi >> 3, q = qi & 7;
    const int a16 = (((r * 64 + q * 8)) ^ ((r & 7) << 4)) >> 1;
    const u32 p0 = cvtpk(sreg[i].x, sreg[i].y);
    const u32 p1 = cvtpk(sreg[i].z, sreg[i].w);
    *reinterpret_cast<uint2*>(&lA[0][a16]) = make_uint2(p0, p1);
  }

#pragma unroll
  for (int kt = 0; kt < 12; ++kt) {
    const int cur = kt & 1;
    if (kt + 1 < 12) {
#pragma unroll
      for (int i = 0; i < 4; ++i) {
        const int qi = t + 256 * i;
        const int r = qi >> 3, q = qi & 7;
        const int grow = row0 + r;
        sreg[i] = (grow < NP)
                      ? *reinterpret_cast<const float4*>(px + (size_t)grow * 384 +
                                                         (kt + 1) * 32 + q * 4)
                      : make_float4(0.f, 0.f, 0.f, 0.f);
      }
    }
    __syncthreads();
#pragma unroll
    for (int rt = 0; rt < 8; ++rt) {
      const short8 af =
          *reinterpret_cast<const short8*>(&lA[cur][(fr_base + rt * 1024) >> 1]);
      acc[rt] = __builtin_amdgcn_mfma_f32_16x16x32_bf16(af, bf[kt], acc[rt], 0, 0, 0);
    }
    if (kt + 1 < 12) {
#pragma unroll
      for (int i = 0; i < 4; ++i) {
        const int qi = t + 256 * i;
        const int r = qi >> 3, q = qi & 7;
        const int a16 = (((r * 64 + q * 8)) ^ ((r & 7) << 4)) >> 1;
        const u32 p0 = cvtpk(sreg[i].x, sreg[i].y);
        const u32 p1 = cvtpk(sreg[i].z, sreg[i].w);
        *reinterpret_cast<uint2*>(&lA[cur ^ 1][a16]) = make_uint2(p0, p1);
      }
    }
  }

#pragma unroll
  for (int rt = 0; rt < 8; ++rt) {
#pragma unroll
    for (int r = 0; r < 4; ++r) {
      const int grow = row0 + rt * 16 + (l >> 4) * 4 + r;
      if (grow < NP)
        xb[(size_t)grow * 64 + n0] = f2bf(fmaxf(acc[rt][r] + bv, 0.f));
    }
  }
}

// ---------------------------------------------------------------------------
// Fused fp32->bf16 conversion of all 4 embedding tables into xb.
// ---------------------------------------------------------------------------
__global__ void cvt_emb_kernel(const float* __restrict__ ue, const float* __restrict__ be,
                               const float* __restrict__ ce, const float* __restrict__ se,
                               u16* __restrict__ xb) {
  const int i = blockIdx.x * 256 + threadIdx.x;
  const int totalQ = (NU + NBR + NCAT + NSH) * 16;
  if (i >= totalQ) return;
  const int row = i >> 4, q = i & 15;
  const float* src;
  int lrow;
  if (row < NU) {
    src = ue; lrow = row;
  } else if (row < NU + NBR) {
    src = be; lrow = row - NU;
  } else if (row < NU + NBR + NCAT) {
    src = ce; lrow = row - NU - NBR;
  } else {
    src = se; lrow = row - NU - NBR - NCAT;
  }
  const float4 v = reinterpret_cast<const float4*>(src)[(size_t)lrow * 16 + q];
  ushort4 o;
  o.x = f2bf(v.x);
  o.y = f2bf(v.y);
  o.z = f2bf(v.z);
  o.w = f2bf(v.w);
  reinterpret_cast<ushort4*>(xb + (size_t)(OFF_U + row) * 64)[q] = o;
}

// ---------------------------------------------------------------------------
// Directed-entry decode. i in [0, 2*nE).
// ---------------------------------------------------------------------------
__device__ __forceinline__ void decode_edge(
    int i, const int* pbs, const int* pbd, const int* pcs, const int* pcd,
    const int* pss, const int* psd, const int* ups, const int* upd,
    int nPB, int nPC, int nPS, int& a, int& b) {
  const int d = i & 1;
  int eu = i >> 1;
  int a0, b0;
  if (eu < nPB) {
    a0 = pbs[eu]; b0 = pbd[eu] + OFF_B;
  } else {
    eu -= nPB;
    if (eu < nPC) {
      a0 = pcs[eu]; b0 = pcd[eu] + OFF_C;
    } else {
      eu -= nPC;
      if (eu < nPS) {
        a0 = pss[eu]; b0 = psd[eu] + OFF_S;
      } else {
        eu -= nPS;
        a0 = ups[eu] + OFF_U; b0 = upd[eu];
      }
    }
  }
  a = d ? b0 : a0;
  b = d ? a0 : b0;
}

#define EDGE_ARGS const int* __restrict__ pbs, const int* __restrict__ pbd, \
                  const int* __restrict__ pcs, const int* __restrict__ pcd, \
                  const int* __restrict__ pss, const int* __restrict__ psd, \
                  const int* __restrict__ ups, const int* __restrict__ upd, \
                  int nPB, int nPC, int nPS, int nD
#define EDGE_PASS pbs, pbd, pcs, pcd, pss, psd, ups, upd, nPB, nPC, nPS

// ---------------------------------------------------------------------------
// 1. Global histogram of directed entries per node-bin (34k global atomics).
// ---------------------------------------------------------------------------
__global__ __launch_bounds__(256) void bin_count_kernel(EDGE_ARGS,
                                                        int* __restrict__ binCnt) {
  __shared__ int lh[NBINS];
  const int t = threadIdx.x;
  if (t < NBINS) lh[t] = 0;
  __syncthreads();
  for (int i = blockIdx.x * 256 + t; i < nD; i += gridDim.x * 256) {
    int a, b;
    decode_edge(i, EDGE_PASS, a, b);
    (void)b;
    atomicAdd(&lh[bin_of(a)], 1);
  }
  __syncthreads();
  if (t < NBINS && lh[t] > 0) atomicAdd(&binCnt[t], lh[t]);
}

// 2. Tiny scan: binCnt[NBINS] -> binBase[NBINS+1]; init gcur.
__global__ void bin_scan_kernel(const int* __restrict__ binCnt, int* __restrict__ binBase,
                                int* __restrict__ gcur) {
  __shared__ int base[NBINS + 1];
  if (threadIdx.x == 0) {
    int run = 0;
    for (int b = 0; b < NBINS; ++b) {
      base[b] = run;
      run += binCnt[b];
    }
    base[NBINS] = run;
  }
  __syncthreads();
  if (threadIdx.x <= NBINS) binBase[threadIdx.x] = base[threadIdx.x];
  if (threadIdx.x < NBINS) gcur[threadIdx.x * 16] = base[threadIdx.x];
}

// ---------------------------------------------------------------------------
// 3. Two-phase block binning by node-bin: LDS hist -> one gcur reserve per
//    bin per block -> re-decode (L2-hot) -> grouped coalesced record writes.
// ---------------------------------------------------------------------------
__global__ __launch_bounds__(256) void bin_scatter_kernel(EDGE_ARGS,
                                                          uint2* __restrict__ gbuf,
                                                          int* __restrict__ gcur) {
  __shared__ int lh[NBINS];
  __shared__ int gb[NBINS];
  __shared__ int ofs[NBINS];
  const int t = threadIdx.x;
  const int per = (nD + gridDim.x - 1) / gridDim.x;
  const int start = blockIdx.x * per;
  const int end = (start + per < nD) ? (start + per) : nD;

  if (t < NBINS) {
    lh[t] = 0;
    ofs[t] = 0;
  }
  __syncthreads();
  for (int i = start + t; i < end; i += 256) {
    int a, b;
    decode_edge(i, EDGE_PASS, a, b);
    (void)b;
    atomicAdd(&lh[bin_of(a)], 1);
  }
  __syncthreads();
  if (t < NBINS && lh[t] > 0) gb[t] = atomicAdd(&gcur[t * 16], lh[t]);
  __syncthreads();
  for (int i = start + t; i < end; i += 256) {
    int a, b;
    decode_edge(i, EDGE_PASS, a, b);
    const int bb = bin_of(a);
    const int d = atomicAdd(&ofs[bb], 1);
    gbuf[gb[bb] + d] = make_uint2((u32)a, (u32)b);
  }
}

// ---------------------------------------------------------------------------
// 4. Per-bin-slice node counting: LDS counters, coalesced partial writes.
//    grid = NBINS*4; block (bin, s) owns records slice s/4 of bin.
// ---------------------------------------------------------------------------
__global__ __launch_bounds__(256) void count_nodes_kernel(
    const uint2* __restrict__ gbuf, const int* __restrict__ binBase,
    int* __restrict__ cntp) {
  __shared__ int cnt[8192];
  const int bin = blockIdx.x >> 2, s = blockIdx.x & 3;
  int n0, n1;
  bin_range(bin, n0, n1);
  const int rb = binBase[bin], re = binBase[bin + 1];
  const int len = re - rb;
  const int s0 = rb + (len * s) / 4;
  const int s1 = rb + (len * (s + 1)) / 4;
  for (int i = threadIdx.x; i < 8192; i += 256) cnt[i] = 0;
  __syncthreads();
  for (int r = s0 + threadIdx.x; r < s1; r += 256)
    atomicAdd(&cnt[(int)gbuf[r].x - n0], 1);
  __syncthreads();
  for (int n = n0 + threadIdx.x; n < n1; n += 256)
    cntp[s * NN + n] = cnt[n - n0];
}

// 3-kernel exclusive scan over sum of 4 partials -> rowptr[NN+1]
__global__ __launch_bounds__(256) void scan1_kernel(const int* __restrict__ cntp,
                                                    int* __restrict__ blockSums, int n) {
  __shared__ int sdata[256];
  const int base = blockIdx.x * 1024;
  int s = 0;
  for (int i = threadIdx.x; i < 1024; i += 256) {
    int idx = base + i;
    if (idx < n)
      s += cntp[idx] + cntp[NN + idx] + cntp[2 * NN + idx] + cntp[3 * NN + idx];
  }
  sdata[threadIdx.x] = s;
  __syncthreads();
  for (int off = 128; off > 0; off >>= 1) {
    if (threadIdx.x < off) sdata[threadIdx.x] += sdata[threadIdx.x + off];
    __syncthreads();
  }
  if (threadIdx.x == 0) blockSums[blockIdx.x] = sdata[0];
}

__global__ __launch_bounds__(512) void scan2_kernel(int* __restrict__ blockSums, int nb) {
  __shared__ int sd[512];
  const int t = threadIdx.x;
  const int v = (t < nb) ? blockSums[t] : 0;
  sd[t] = v;
  __syncthreads();
  for (int off = 1; off < 512; off <<= 1) {
    int add = (t >= off) ? sd[t - off] : 0;
    __syncthreads();
    sd[t] += add;
    __syncthreads();
  }
  if (t < nb) blockSums[t] = sd[t] - v;  // exclusive
}

__global__ __launch_bounds__(256) void scan3_kernel(const int* __restrict__ cntp,
                                                    const int* __restrict__ blockSums,
                                                    int* __restrict__ rowptr, int n) {
  __shared__ int wsum[4];
  const int base = blockIdx.x * 1024;
  const int t = threadIdx.x, lane = t & 63, wid = t >> 6;
  const int idx0 = base + t * 4;
  int v[4];
#pragma unroll
  for (int j = 0; j < 4; ++j) {
    int idx = idx0 + j;
    v[j] = (idx < n)
               ? cntp[idx] + cntp[NN + idx] + cntp[2 * NN + idx] + cntp[3 * NN + idx]
               : 0;
  }
  const int s = v[0] + v[1] + v[2] + v[3];
  int incl = s;
  for (int off = 1; off < 64; off <<= 1) {
    int tt = __shfl_up(incl, off);
    if (lane >= off) incl += tt;
  }
  if (lane == 63) wsum[wid] = incl;
  __syncthreads();
  int wOff = 0;
#pragma unroll
  for (int w = 0; w < 4; ++w)
    if (w < wid) wOff += wsum[w];
  int run = blockSums[blockIdx.x] + wOff + (incl - s);
#pragma unroll
  for (int j = 0; j < 4; ++j) {
    int idx = idx0 + j;
    if (idx < n) {
      rowptr[idx] = run;
      run += v[j];
      if (idx == n - 1) rowptr[n] = run;
    }
  }
}

// ---------------------------------------------------------------------------
// 6. Final fill: LDS cursor (rowptr + prefix of earlier slices), LDS-atomic
//    position assignment, scatter confined to bin's eidx window (L2-merged).
// ---------------------------------------------------------------------------
__global__ __launch_bounds__(256) void fill_scatter_kernel(
    const uint2* __restrict__ gbuf, const int* __restrict__ binBase,
    const int* __restrict__ rowptr, const int* __restrict__ cntp,
    int* __restrict__ eidx) {
  __shared__ int cur[8192];
  const int bin = blockIdx.x >> 2, s = blockIdx.x & 3;
  int n0, n1;
  bin_range(bin, n0, n1);
  const int rb = binBase[bin], re = binBase[bin + 1];
  const int len = re - rb;
  const int s0 = rb + (len * s) / 4;
  const int s1 = rb + (len * (s + 1)) / 4;
  for (int n = n0 + threadIdx.x; n < n1; n += 256) {
    int c = rowptr[n];
    if (s > 0) c += cntp[n];
    if (s > 1) c += cntp[NN + n];
    if (s > 2) c += cntp[2 * NN + n];
    cur[n - n0] = c;
  }
  __syncthreads();
  for (int r = s0 + threadIdx.x; r < s1; r += 256) {
    const uint2 rec = gbuf[r];
    const int p = atomicAdd(&cur[(int)rec.x - n0], 1);
    eidx[p] = (int)rec.y;
  }
}

// ---------------------------------------------------------------------------
// Gather-mean v2: sout[node][:] = bf16(mean_{j in N(node)} xin[j][:]).
// 8 lanes per row (uint4 = 16B/lane -> 8 rows per vmem instr); 16 edges in
// flight per iter; EXEC-MASKED tail loads (no wasted row fetches); 3-round
// shfl_xor dim reduction once per node; fp32 accumulate.
// ---------------------------------------------------------------------------
__global__ __launch_bounds__(256) void gather_mean_kernel(
    const int* __restrict__ rowptr, const int* __restrict__ eidx,
    const uint4* __restrict__ xin, uint4* __restrict__ sout) {
  const int lane = threadIdx.x & 63;
  const int q = lane & 7;   // 16B dim-slice within the 128B row
  const int h = lane >> 3;  // edge slot 0..7
  const int wid0 = blockIdx.x * 4 + (threadIdx.x >> 6);
  const int nW = gridDim.x * 4;
  for (int node = wid0; node < NN; node += nW) {
    const int r0 = rowptr[node], r1 = rowptr[node + 1];
    float s0 = 0.f, s1 = 0.f, s2 = 0.f, s3 = 0.f, s4 = 0.f, s5 = 0.f, s6 = 0.f,
          s7 = 0.f;
    for (int e = r0; e < r1; e += 16) {
      const int ee0 = e + h;
      const int ee1 = e + 8 + h;
      uint4 va = make_uint4(0u, 0u, 0u, 0u);
      uint4 vb = make_uint4(0u, 0u, 0u, 0u);
      if (ee0 < r1) va = xin[(size_t)eidx[ee0] * 8 + q];  // exec-masked load
      if (ee1 < r1) vb = xin[(size_t)eidx[ee1] * 8 + q];
      s0 += uasf(va.x << 16) + uasf(vb.x << 16);
      s1 += uasf(va.x & 0xffff0000u) + uasf(vb.x & 0xffff0000u);
      s2 += uasf(va.y << 16) + uasf(vb.y << 16);
      s3 += uasf(va.y & 0xffff0000u) + uasf(vb.y & 0xffff0000u);
      s4 += uasf(va.z << 16) + uasf(vb.z << 16);
      s5 += uasf(va.z & 0xffff0000u) + uasf(vb.z & 0xffff0000u);
      s6 += uasf(va.w << 16) + uasf(vb.w << 16);
      s7 += uasf(va.w & 0xffff0000u) + uasf(vb.w & 0xffff0000u);
    }
#pragma unroll
    for (int off = 8; off < 64; off <<= 1) {
      s0 += __shfl_xor(s0, off);
      s1 += __shfl_xor(s1, off);
      s2 += __shfl_xor(s2, off);
      s3 += __shfl_xor(s3, off);
      s4 += __shfl_xor(s4, off);
      s5 += __shfl_xor(s5, off);
      s6 += __shfl_xor(s6, off);
      s7 += __shfl_xor(s7, off);
    }
    if (h == 0) {
      const int deg = r1 - r0;
      const float inv = (deg > 0) ? (1.f / (float)deg) : 1.f;
      uint4 o;
      o.x = cvtpk(s0 * inv, s1 * inv);
      o.y = cvtpk(s2 * inv, s3 * inv);
      o.z = cvtpk(s4 * inv, s5 * inv);
      o.w = cvtpk(s6 * inv, s7 * inv);
      sout[(size_t)node * 8 + q] = o;
    }
  }
}

// ---------------------------------------------------------------------------
// Dense layer GEMM: out = act(S @ Wl + bl + X @ Wr), S,X bf16 [NN][64].
// ---------------------------------------------------------------------------
template <int DOUT, bool RELU>
__global__ __launch_bounds__(256) void layer_gemm_kernel(
    const u32* __restrict__ S, const u32* __restrict__ X,
    const float* __restrict__ Wl, const float* __restrict__ bl,
    const float* __restrict__ Wr, void* __restrict__ outv) {
  constexpr int NC = DOUT / 4;
  constexpr int NR = 256 / NC;
  constexpr int R = 128 / NR;
  __shared__ __align__(16) u32 lS[128 * 32];
  __shared__ __align__(16) u32 lX[128 * 32];
  __shared__ __align__(16) float lWl[64 * DOUT];
  __shared__ __align__(16) float lWr[64 * DOUT];
  const int t = threadIdx.x;
  const int row0 = blockIdx.x * 128;

#pragma unroll
  for (int i = 0; i < (64 * DOUT) / 1024; ++i) {
    const int idx = i * 256 + t;
    reinterpret_cast<float4*>(lWl)[idx] = reinterpret_cast<const float4*>(Wl)[idx];
    reinterpret_cast<float4*>(lWr)[idx] = reinterpret_cast<const float4*>(Wr)[idx];
  }
#pragma unroll
  for (int i = 0; i < 4; ++i) {
    const int idx = i * 256 + t;
    const int r = idx >> 3, c = idx & 7;
    uint4 vs = make_uint4(0u, 0u, 0u, 0u), vx = vs;
    if (row0 + r < NN) {
      vs = reinterpret_cast<const uint4*>(S)[(size_t)(row0 + r) * 8 + c];
      vx = reinterpret_cast<const uint4*>(X)[(size_t)(row0 + r) * 8 + c];
    }
    reinterpret_cast<uint4*>(lS)[idx] = vs;
    reinterpret_cast<uint4*>(lX)[idx] = vx;
  }
  __syncthreads();

  const int cg = t % NC, rg = t / NC;
  const int c0 = cg * 4;
  float acc[R][4];
#pragma unroll
  for (int r = 0; r < R; ++r)
#pragma unroll
    for (int c = 0; c < 4; ++c) acc[r][c] = 0.f;

  for (int kq = 0; kq < 16; ++kq) {
    float4 wl4[4], wr4[4];
#pragma unroll
    for (int j = 0; j < 4; ++j) {
      wl4[j] = *reinterpret_cast<const float4*>(&lWl[(kq * 4 + j) * DOUT + c0]);
      wr4[j] = *reinterpret_cast<const float4*>(&lWr[(kq * 4 + j) * DOUT + c0]);
    }
#pragma unroll
    for (int r = 0; r < R; ++r) {
      const int row = rg * R + r;
      const uint2 sv = *reinterpret_cast<const uint2*>(&lS[row * 32 + kq * 2]);
      const uint2 xv = *reinterpret_cast<const uint2*>(&lX[row * 32 + kq * 2]);
      const float sf[4] = {uasf(sv.x << 16), uasf(sv.x & 0xffff0000u),
                           uasf(sv.y << 16), uasf(sv.y & 0xffff0000u)};
      const float xf[4] = {uasf(xv.x << 16), uasf(xv.x & 0xffff0000u),
                           uasf(xv.y << 16), uasf(xv.y & 0xffff0000u)};
#pragma unroll
      for (int j = 0; j < 4; ++j) {
        acc[r][0] = fmaf(sf[j], wl4[j].x, acc[r][0]);
        acc[r][1] = fmaf(sf[j], wl4[j].y, acc[r][1]);
        acc[r][2] = fmaf(sf[j], wl4[j].z, acc[r][2]);
        acc[r][3] = fmaf(sf[j], wl4[j].w, acc[r][3]);
        acc[r][0] = fmaf(xf[j], wr4[j].x, acc[r][0]);
        acc[r][1] = fmaf(xf[j], wr4[j].y, acc[r][1]);
        acc[r][2] = fmaf(xf[j], wr4[j].z, acc[r][2]);
        acc[r][3] = fmaf(xf[j], wr4[j].w, acc[r][3]);
      }
    }
  }

  const float b0 = bl[c0 + 0], b1 = bl[c0 + 1], b2 = bl[c0 + 2], b3 = bl[c0 + 3];
#pragma unroll
  for (int r = 0; r < R; ++r) {
    const int grow = row0 + rg * R + r;
    if (grow < NN) {
      float o0 = acc[r][0] + b0, o1 = acc[r][1] + b1, o2 = acc[r][2] + b2, o3 = acc[r][3] + b3;
      if (RELU) {
        o0 = fmaxf(o0, 0.f); o1 = fmaxf(o1, 0.f); o2 = fmaxf(o2, 0.f); o3 = fmaxf(o3, 0.f);
      }
      if (DOUT == 64) {
        ushort4 o;
        o.x = f2bf(o0); o.y = f2bf(o1); o.z = f2bf(o2); o.w = f2bf(o3);
        *reinterpret_cast<ushort4*>((u16*)outv + (size_t)grow * 64 + c0) = o;
      } else {
        float4 o = make_float4(o0, o1, o2, o3);
        *reinterpret_cast<float4*>((float*)outv + (size_t)grow * 32 + c0) = o;
      }
    }
  }
}

// ---------------------------------------------------------------------------
extern "C" void kernel_launch(void* const* d_in, const int* in_sizes, int n_in,
                              void* d_out, int out_size, void* d_ws, size_t ws_size,
                              hipStream_t stream) {
  const float* product_x = (const float*)d_in[0];
  const float* user_emb = (const float*)d_in[1];
  const float* brand_emb = (const float*)d_in[2];
  const float* cat_emb = (const float*)d_in[3];
  const float* shop_emb = (const float*)d_in[4];
  const float* proj_W = (const float*)d_in[5];
  const float* proj_b = (const float*)d_in[6];
  const float* c1_Wl = (const float*)d_in[7];
  const float* c1_bl = (const float*)d_in[8];
  const float* c1_Wr = (const float*)d_in[9];
  const float* c2_Wl = (const float*)d_in[10];
  const float* c2_bl = (const float*)d_in[11];
  const float* c2_Wr = (const float*)d_in[12];
  const int* pb_src = (const int*)d_in[13];
  const int* pb_dst = (const int*)d_in[14];
  const int* pc_src = (const int*)d_in[15];
  const int* pc_dst = (const int*)d_in[16];
  const int* ps_src = (const int*)d_in[17];
  const int* ps_dst = (const int*)d_in[18];
  const int* up_src = (const int*)d_in[19];
  const int* up_dst = (const int*)d_in[20];
  const int nPB = in_sizes[13], nPC = in_sizes[15], nPS = in_sizes[17], nUP = in_sizes[19];
  const int nE = nPB + nPC + nPS + nUP;
  const int nD = 2 * nE;

  // workspace layout (bf16 tables as u16/u32 views)
  u16* xb = (u16*)d_ws;                          // [NN*64] bf16
  u16* out1 = xb + (size_t)NN * 64;              // [NN*64] bf16
  u16* sbuf = out1 + (size_t)NN * 64;            // [NN*64] bf16 (reused both layers)
  int* eidx = (int*)(sbuf + (size_t)NN * 64);    // [nD]
  int* rowptr = eidx + nD;                       // [NN+1]
  int* blockSums = rowptr + (NN + 1);            // [512]
  int* binCnt = blockSums + 512;                 // [128]
  int* binBase = binCnt + 128;                   // [NBINS+1]
  int* gcur = binBase + 128;                     // [NBINS*16] padded
  // aliased scratch (dead before their regions' first real write):
  uint2* gbuf = (uint2*)sbuf;  // [nD] 28.8MB <= 39.4MB; dead until gather1 writes sbuf
  int* cntp = (int*)out1;      // [4*NN] 4.9MB <= 39.4MB; dead until gemm1 writes out1

  hipMemsetAsync(binCnt, 0, 128 * sizeof(int), stream);

  bin_count_kernel<<<512, 256, 0, stream>>>(pb_src, pb_dst, pc_src, pc_dst, ps_src, ps_dst,
                                            up_src, up_dst, nPB, nPC, nPS, nD, binCnt);
  bin_scan_kernel<<<1, 128, 0, stream>>>(binCnt, binBase, gcur);
  bin_scatter_kernel<<<512, 256, 0, stream>>>(pb_src, pb_dst, pc_src, pc_dst, ps_src, ps_dst,
                                              up_src, up_dst, nPB, nPC, nPS, nD, gbuf, gcur);
  count_nodes_kernel<<<NBINS * 4, 256, 0, stream>>>(gbuf, binBase, cntp);

  const int nb = (NN + 1023) / 1024;  // 301
  scan1_kernel<<<nb, 256, 0, stream>>>(cntp, blockSums, NN);
  scan2_kernel<<<1, 512, 0, stream>>>(blockSums, nb);
  scan3_kernel<<<nb, 256, 0, stream>>>(cntp, blockSums, rowptr, NN);

  fill_scatter_kernel<<<NBINS * 4, 256, 0, stream>>>(gbuf, binBase, rowptr, cntp, eidx);

  proj_mfma_kernel<<<(NP + 127) / 128, 256, 0, stream>>>(product_x, proj_W, proj_b, xb);
  cvt_emb_kernel<<<((NU + NBR + NCAT + NSH) * 16 + 255) / 256, 256, 0, stream>>>(
      user_emb, brand_emb, cat_emb, shop_emb, xb);

  // Layer 1
  gather_mean_kernel<<<4096, 256, 0, stream>>>(rowptr, eidx, (const uint4*)xb,
                                               (uint4*)sbuf);
  layer_gemm_kernel<64, true><<<(NN + 127) / 128, 256, 0, stream>>>(
      (const u32*)sbuf, (const u32*)xb, c1_Wl, c1_bl, c1_Wr, out1);
  // Layer 2
  gather_mean_kernel<<<4096, 256, 0, stream>>>(rowptr, eidx, (const uint4*)out1,
                                               (uint4*)sbuf);
  layer_gemm_kernel<32, false><<<(NN + 127) / 128, 256, 0, stream>>>(
      (const u32*)sbuf, (const u32*)out1, c2_Wl, c2_bl, c2_Wr, d_out);
}